// Round 1
// baseline (394.097 us; speedup 1.0000x reference)
//
#include <hip/hip_runtime.h>

#define DIMC 128
#define NHEADS 4
#define HD 32
#define HID 256
#define BB 4
#define HH_ 128
#define WW_ 128
#define HW 16384
#define RS 16
#define STEP 14
#define NR 9
#define NREGB 81
#define NREG 324
#define TT 256

typedef unsigned short bfu;  // bf16 bits
typedef __attribute__((ext_vector_type(8))) short bf16x8;
typedef __attribute__((ext_vector_type(4))) float f32x4;

__device__ __forceinline__ float bf2f(bfu u) {
  return __uint_as_float(((unsigned int)u) << 16);
}
__device__ __forceinline__ bfu f2bf(float f) {
  unsigned int i = __float_as_uint(f);
  unsigned int r = i + 0x7fffu + ((i >> 16) & 1u);
  return (bfu)(r >> 16);
}
__device__ __forceinline__ float gelu_exact(float x) {
  return 0.5f * x * (1.0f + erff(x * 0.70710678118654752f));
}

// KPREP: bid 0..23 wqkvT [kg16][n384][8k]; bid 24 zero bnacc;
// bid 25..40 ap0; bid 41..56 ap2; bid 57..64 awout
__global__ __launch_bounds__(256) void kprep(
    const float* __restrict__ wqkv, const float* __restrict__ wp0,
    const float* __restrict__ wp2, const float* __restrict__ wout,
    bfu* __restrict__ wqkvT, bfu* __restrict__ ap0, bfu* __restrict__ ap2,
    bfu* __restrict__ awout, float* __restrict__ bnacc) {
  int bid = blockIdx.x;
  int tid = threadIdx.x;
  if (bid < 24) {
    int task = bid * 256 + tid;  // kg*384 + n
    int kg = task / 384, n = task % 384;
    bfu tmp[8];
    #pragma unroll
    for (int j = 0; j < 8; ++j) tmp[j] = f2bf(wqkv[(kg * 8 + j) * 384 + n]);
    *(uint4*)&wqkvT[(size_t)kg * 3072 + n * 8] = *(const uint4*)tmp;
  } else if (bid == 24) {
    bnacc[tid] = 0.f;
    bnacc[256 + tid] = 0.f;
  } else if (bid < 41) {
    int task = (bid - 25) * 256 + tid;  // kg*256 + f
    int kg = task >> 8, f = task & 255;
    bfu tmp[8];
    #pragma unroll
    for (int j = 0; j < 8; ++j) tmp[j] = f2bf(wp0[(kg * 8 + j) * 256 + f]);
    *(uint4*)&ap0[((size_t)kg * 256 + f) * 8] = *(const uint4*)tmp;
  } else if (bid < 57) {
    int task = (bid - 41) * 256 + tid;  // kg*128 + c
    int kg = task >> 7, c = task & 127;
    bfu tmp[8];
    #pragma unroll
    for (int j = 0; j < 8; ++j) tmp[j] = f2bf(wp2[(kg * 8 + j) * 128 + c]);
    *(uint4*)&ap2[((size_t)kg * 128 + c) * 8] = *(const uint4*)tmp;
  } else {
    int task = (bid - 57) * 256 + tid;  // kg*128 + c
    int kg = task >> 7, c = task & 127;
    bfu tmp[8];
    #pragma unroll
    for (int j = 0; j < 8; ++j) tmp[j] = f2bf(wout[(kg * 8 + j) * 128 + c]);
    *(uint4*)&awout[((size_t)kg * 128 + c) * 8] = *(const uint4*)tmp;
  }
}

// K1: gather -> tok bf16 [reg][c][t]; aln bf16 blocked [reg][g=c/8][t][8c]
__global__ __launch_bounds__(256) void k1_gather(
    const float* __restrict__ x, const float* __restrict__ g,
    const float* __restrict__ bia, bfu* __restrict__ tok,
    bfu* __restrict__ aln) {
  int reg = blockIdx.x;
  int b = reg / NREGB, ij = reg % NREGB;
  int i = ij / NR, j = ij % NR;
  int t = threadIdx.x;
  int r = t >> 4, s = t & 15;
  int hh = i * STEP + r, ww = j * STEP + s;
  const float* xp = x + (size_t)b * DIMC * HW + (size_t)hh * WW_ + ww;
  bfu* tp = tok + (size_t)reg * DIMC * TT + t;
  float sum = 0.f, sq = 0.f;
  #pragma unroll 4
  for (int c = 0; c < DIMC; ++c) {
    float v = xp[(size_t)c * HW];
    tp[c * TT] = f2bf(v);
    sum += v;
    sq = fmaf(v, v, sq);
  }
  float mu = sum * (1.0f / DIMC);
  float var = sq * (1.0f / DIMC) - mu * mu;
  float rstd = rsqrtf(var + 1e-5f);
  bfu* ap = aln + (size_t)reg * 32768 + t * 8;
  #pragma unroll
  for (int gidx = 0; gidx < 16; ++gidx) {
    bfu tmp[8];
    #pragma unroll
    for (int jj = 0; jj < 8; ++jj) {
      int c = gidx * 8 + jj;
      float vv = xp[(size_t)c * HW];  // L2-hot re-read
      tmp[jj] = f2bf((vv - mu) * rstd * g[c] + bia[c]);
    }
    *(uint4*)&ap[(size_t)gidx * 2048] = *(const uint4*)tmp;
  }
}

// K23: fused per-(region,head) QKV projection + attention.
// Replaces k2_qkv + k3_attn; qkv never touches HBM.
// GEMM: wave w computes tokens w*64..w*64+63 x 96 head-cols (q|k|v, 32 each),
// scatters f2bf(acc) into sQ/sK/vperm (exact layouts the K3 body reads),
// then the unmodified K3 attention body runs out of LDS.
__global__ __launch_bounds__(256) void k23_fused(
    const bfu* __restrict__ aln, const bfu* __restrict__ wqkvT,
    bfu* __restrict__ o) {
  int reg = blockIdx.x;
  int h = blockIdx.y;
  __shared__ __align__(16) bfu sQ[256 * 40];        // [tok][d32 +8pad] 20.5KB
  __shared__ __align__(16) bfu sK[256 * 40];        // 20.5KB
  __shared__ __align__(16) bfu vperm[8 * 4 * 264];  // 16.9KB
  int tid = threadIdx.x;
  int wave = tid >> 6, lane = tid & 63;
  int quad = lane >> 4, n16 = lane & 15;

  // ---- QKV GEMM for this head: [256 tok x 96 cols] = aln @ W[:, cols(h)]
  const bfu* ab = aln + (size_t)reg * 32768 + (wave * 64 + n16) * 8;
  int colb[6];
  colb[0] = h * 32;        // q lo
  colb[1] = h * 32 + 16;   // q hi
  colb[2] = 128 + h * 32;  // k lo
  colb[3] = 144 + h * 32;  // k hi
  colb[4] = 256 + h * 32;  // v lo
  colb[5] = 272 + h * 32;  // v hi
  f32x4 acc[4][6];
  #pragma unroll
  for (int m = 0; m < 4; ++m)
    #pragma unroll
    for (int nt = 0; nt < 6; ++nt) acc[m][nt] = (f32x4){0.f, 0.f, 0.f, 0.f};
  #pragma unroll
  for (int ph = 0; ph < 4; ++ph) {
    int gg = ph * 4 + quad;
    bf16x8 af[4];
    #pragma unroll
    for (int m = 0; m < 4; ++m)
      af[m] = *(const bf16x8*)&ab[(size_t)gg * 2048 + m * 128];
    const bfu* bgg = wqkvT + (size_t)gg * 3072;
    bf16x8 bfr[6];
    #pragma unroll
    for (int nt = 0; nt < 6; ++nt)
      bfr[nt] = *(const bf16x8*)&bgg[(colb[nt] + n16) * 8];
    #pragma unroll
    for (int m = 0; m < 4; ++m)
      #pragma unroll
      for (int nt = 0; nt < 6; ++nt)
        acc[m][nt] =
            __builtin_amdgcn_mfma_f32_16x16x32_bf16(af[m], bfr[nt], acc[m][nt], 0, 0, 0);
  }
  // ---- scatter acc -> LDS (C/D map: row = quad*4+r, col = n16)
  // token t = wave*64 + m*16 + quad*4 + r
  // vperm token coords: g = t>>5, qd = quad, jt = (m&1)*4 + r
  #pragma unroll
  for (int m = 0; m < 4; ++m) {
    int g = wave * 2 + (m >> 1);
    int jt = (m & 1) * 4;
    #pragma unroll
    for (int r = 0; r < 4; ++r) {
      int t = wave * 64 + m * 16 + quad * 4 + r;
      sQ[t * 40 + n16] = f2bf(acc[m][0][r]);
      sQ[t * 40 + 16 + n16] = f2bf(acc[m][1][r]);
      sK[t * 40 + n16] = f2bf(acc[m][2][r]);
      sK[t * 40 + 16 + n16] = f2bf(acc[m][3][r]);
      bfu* vd = &vperm[(g * 4 + quad) * 264 + jt + r];
      vd[n16 * 8] = f2bf(acc[m][4][r]);
      vd[(16 + n16) * 8] = f2bf(acc[m][5][r]);
    }
  }
  __syncthreads();

  // ---- attention (K3 body, Q from LDS) ----
  const f32x4 zero = {0.f, 0.f, 0.f, 0.f};
  const float scale = 0.17677669529663687f;  // 1/sqrt(32)
  for (int mi = 0; mi < 4; ++mi) {
    int mt = wave * 4 + mi;
    bf16x8 qf = *(const bf16x8*)&sQ[(mt * 16 + n16) * 40 + quad * 8];
    f32x4 st[16];
    #pragma unroll
    for (int T = 0; T < 16; ++T) {
      bf16x8 kf = *(const bf16x8*)&sK[(T * 16 + n16) * 40 + quad * 8];
      st[T] = __builtin_amdgcn_mfma_f32_16x16x32_bf16(kf, qf, zero, 0, 0, 0);
    }
    float m = st[0][0];
    #pragma unroll
    for (int T = 0; T < 16; ++T)
      #pragma unroll
      for (int r = 0; r < 4; ++r) m = fmaxf(m, st[T][r]);
    m = fmaxf(m, __shfl_xor(m, 16, 64));
    m = fmaxf(m, __shfl_xor(m, 32, 64));
    float l = 0.f;
    #pragma unroll
    for (int T = 0; T < 16; ++T)
      #pragma unroll
      for (int r = 0; r < 4; ++r) {
        float p = __expf((st[T][r] - m) * scale);
        st[T][r] = p;
        l += p;
      }
    l += __shfl_xor(l, 16, 64);
    l += __shfl_xor(l, 32, 64);
    float inv = 1.0f / l;
    f32x4 oa0 = zero, oa1 = zero;
    #pragma unroll
    for (int g = 0; g < 8; ++g) {
      bfu pk[8];
      #pragma unroll
      for (int r = 0; r < 4; ++r) {
        pk[r] = f2bf(st[2 * g][r]);
        pk[4 + r] = f2bf(st[2 * g + 1][r]);
      }
      bf16x8 pf = *(const bf16x8*)pk;
      bf16x8 va = *(const bf16x8*)&vperm[(g * 4 + quad) * 264 + n16 * 8];
      bf16x8 vb = *(const bf16x8*)&vperm[(g * 4 + quad) * 264 + (16 + n16) * 8];
      oa0 = __builtin_amdgcn_mfma_f32_16x16x32_bf16(va, pf, oa0, 0, 0, 0);
      oa1 = __builtin_amdgcn_mfma_f32_16x16x32_bf16(vb, pf, oa1, 0, 0, 0);
    }
    bfu* ob = o + ((size_t)reg * 256 + mt * 16 + n16) * 128 + h * 32 + quad * 4;
    ushort4 s0, s1;
    s0.x = f2bf(oa0[0] * inv);
    s0.y = f2bf(oa0[1] * inv);
    s0.z = f2bf(oa0[2] * inv);
    s0.w = f2bf(oa0[3] * inv);
    s1.x = f2bf(oa1[0] * inv);
    s1.y = f2bf(oa1[1] * inv);
    s1.z = f2bf(oa1[2] * inv);
    s1.w = f2bf(oa1[3] * inv);
    *(ushort4*)&ob[0] = s0;
    *(ushort4*)&ob[16] = s1;
  }
}

// K4: tok[c][t] (bf16) += o @ w_out + b_out via MFMA, LDS-free
__global__ __launch_bounds__(256) void k4_outproj(
    const bfu* __restrict__ o, const bfu* __restrict__ awout,
    const float* __restrict__ bout, bfu* __restrict__ tok) {
  int reg = blockIdx.x;
  int tt = blockIdx.y;
  int tid = threadIdx.x;
  int wave = tid >> 6, lane = tid & 63;
  int quad = lane >> 4, n16 = lane & 15;
  int t = tt * 64 + wave * 16 + n16;
  const bfu* ob = o + ((size_t)reg * 256 + t) * 128;
  f32x4 acc[8];
  #pragma unroll
  for (int mt = 0; mt < 8; ++mt) acc[mt] = (f32x4){0.f, 0.f, 0.f, 0.f};
  #pragma unroll
  for (int kt = 0; kt < 4; ++kt) {
    bf16x8 bfrag = *(const bf16x8*)&ob[kt * 32 + quad * 8];
    const bfu* arow = awout + ((size_t)(kt * 4 + quad) * 128 + n16) * 8;
    #pragma unroll
    for (int mt = 0; mt < 8; ++mt) {
      bf16x8 afrag = *(const bf16x8*)&arow[mt * 128];
      acc[mt] = __builtin_amdgcn_mfma_f32_16x16x32_bf16(afrag, bfrag, acc[mt], 0, 0, 0);
    }
  }
  bfu* tokr = tok + (size_t)reg * DIMC * TT + t;
  #pragma unroll
  for (int mt = 0; mt < 8; ++mt) {
    #pragma unroll
    for (int r = 0; r < 4; ++r) {
      int c = mt * 16 + quad * 4 + r;
      float val = bf2f(tokr[c * TT]) + acc[mt][r] + bout[c];
      tokr[c * TT] = f2bf(val);
    }
  }
}

// K5: overlap merge (bf16 tok) -> xf fp32 + xln bf16 blocked [b][cg][p][8c]
__global__ __launch_bounds__(512) void k5_merge(
    const bfu* __restrict__ tok, const float* __restrict__ ln2g,
    const float* __restrict__ ln2b, float* __restrict__ xf,
    bfu* __restrict__ xln) {
  int hh = blockIdx.x, b = blockIdx.y;
  int tid = threadIdx.x;
  int w = tid & 127, q = tid >> 7;
  int ilo = (hh >= 2) ? (hh - 2) / 14 : 0;
  int ihi = hh / 14;
  if (ihi > 8) ihi = 8;
  int jlo = (w >= 2) ? (w - 2) / 14 : 0;
  int jhi = w / 14;
  if (jhi > 8) jhi = 8;
  float rcnt = 1.0f / (float)((ihi - ilo + 1) * (jhi - jlo + 1));
  size_t offs[4];
  int nij = 0;
  for (int i = ilo; i <= ihi; ++i)
    for (int j = jlo; j <= jhi; ++j) {
      int reg = b * NREGB + i * NR + j;
      int r = hh - i * STEP, s = w - j * STEP;
      offs[nij++] = (size_t)reg * DIMC * TT + r * 16 + s;
    }
  float* xp = xf + ((size_t)b * DIMC << 14) + hh * WW_ + w;
  float mm[32];
  float sum = 0.f, sq = 0.f;
  int c0 = q * 32;
  for (int cc = 0; cc < 32; ++cc) {
    int c = c0 + cc;
    float s = 0.f;
    for (int k = 0; k < nij; ++k) s += bf2f(tok[offs[k] + c * TT]);
    float m = s * rcnt;
    xp[(size_t)c << 14] = m;
    mm[cc] = m;
    sum += m;
    sq = fmaf(m, m, sq);
  }
  __shared__ float rs[512];
  __shared__ float rq[512];
  __shared__ float muS[128];
  __shared__ float rsdS[128];
  rs[tid] = sum;
  rq[tid] = sq;
  __syncthreads();
  if (tid < 128) {
    float s4 = rs[tid] + rs[tid + 128] + rs[tid + 256] + rs[tid + 384];
    float q4 = rq[tid] + rq[tid + 128] + rq[tid + 256] + rq[tid + 384];
    float mu = s4 * (1.0f / DIMC);
    float var = q4 * (1.0f / DIMC) - mu * mu;
    muS[tid] = mu;
    rsdS[tid] = rsqrtf(var + 1e-5f);
  }
  __syncthreads();
  float mu = muS[w], rstd = rsdS[w];
  int p = hh * WW_ + w;
  #pragma unroll
  for (int gl = 0; gl < 4; ++gl) {
    int gidx = q * 4 + gl;
    bfu tmp[8];
    #pragma unroll
    for (int j = 0; j < 8; ++j) {
      int c = gidx * 8 + j;
      tmp[j] = f2bf((mm[gl * 8 + j] - mu) * rstd * ln2g[c] + ln2b[c]);
    }
    *(uint4*)&xln[(((size_t)(b * 16 + gidx) << 14) + p) * 8] = *(const uint4*)tmp;
  }
}

// K6: ym[b][f][p] = xln @ w_p0 + b_p0 via MFMA
__global__ __launch_bounds__(256) void k6_p0(
    const bfu* __restrict__ xln, const bfu* __restrict__ ap0,
    const float* __restrict__ bp0, bfu* __restrict__ ym) {
  int b = blockIdx.y;
  int ptile = blockIdx.x * 64;
  int tid = threadIdx.x;
  int wv = tid >> 6, lane = tid & 63;
  int quad = lane >> 4, n16 = lane & 15;
  int p = ptile + wv * 16 + n16;
  f32x4 acc[16];
  #pragma unroll
  for (int mt = 0; mt < 16; ++mt) acc[mt] = (f32x4){0.f, 0.f, 0.f, 0.f};
  #pragma unroll
  for (int ph = 0; ph < 4; ++ph) {
    int gg = ph * 4 + quad;
    bf16x8 bfrag = *(const bf16x8*)&xln[(((size_t)(b * 16 + gg) << 14) + p) * 8];
    const bfu* arow = ap0 + ((size_t)gg * 256 + n16) * 8;
    #pragma unroll
    for (int mt = 0; mt < 16; ++mt) {
      bf16x8 afrag = *(const bf16x8*)&arow[mt * 128];
      acc[mt] = __builtin_amdgcn_mfma_f32_16x16x32_bf16(afrag, bfrag, acc[mt], 0, 0, 0);
    }
  }
  #pragma unroll
  for (int mt = 0; mt < 16; ++mt) {
    #pragma unroll
    for (int r = 0; r < 4; ++r) {
      int f = mt * 16 + quad * 4 + r;
      ym[((size_t)(b * HID + f) << 14) + p] = f2bf(acc[mt][r] + bp0[f]);
    }
  }
}

// K7: 5x5 depthwise conv, whole plane in LDS, fused BN partials
__global__ __launch_bounds__(256) void k7_conv(
    const bfu* __restrict__ ym, const float* __restrict__ dwk,
    bfu* __restrict__ ym2, float* __restrict__ bnacc) {
  int bf = blockIdx.x;
  int f = bf & (HID - 1);
  __shared__ bfu sp[128 * 134];
  const bfu* in = ym + ((size_t)bf << 14);
  int tid = threadIdx.x;
  for (int idx = tid; idx < 2048; idx += 256) {
    int r = idx >> 4, c8 = (idx & 15) << 3;
    ushort4 a = *(const ushort4*)&in[(r << 7) + c8];
    ushort4 b = *(const ushort4*)&in[(r << 7) + c8 + 4];
    bfu* d = &sp[r * 134 + c8];
    d[0] = a.x; d[1] = a.y; d[2] = a.z; d[3] = a.w;
    d[4] = b.x; d[5] = b.y; d[6] = b.z; d[7] = b.w;
  }
  float wk[25];
  #pragma unroll
  for (int i = 0; i < 25; ++i) wk[i] = dwk[f * 25 + i];
  __syncthreads();
  int row = tid >> 1, half = (tid & 1) << 6;
  float acc[64];
  #pragma unroll
  for (int i = 0; i < 64; ++i) acc[i] = 0.f;
  #pragma unroll
  for (int ky = 0; ky < 5; ++ky) {
    int y = row + ky - 2;
    if (y < 0 || y >= 128) continue;
    const bfu* rp = &sp[y * 134];
    float win[68];
    #pragma unroll
    for (int c = 0; c < 68; ++c) {
      int cc = half + c - 2;
      win[c] = (cc >= 0 && cc < 128) ? bf2f(rp[cc]) : 0.f;
    }
    #pragma unroll
    for (int kx = 0; kx < 5; ++kx) {
      float wv = wk[ky * 5 + kx];
      #pragma unroll
      for (int i = 0; i < 64; ++i) acc[i] = fmaf(win[i + kx], wv, acc[i]);
    }
  }
  float s = 0.f, sq = 0.f;
  #pragma unroll
  for (int i = 0; i < 64; ++i) {
    s += acc[i];
    sq = fmaf(acc[i], acc[i], sq);
  }
  bfu* op = ym2 + ((size_t)bf << 14) + (row << 7) + half;
  #pragma unroll
  for (int g8 = 0; g8 < 8; ++g8) {
    bfu tmp[8];
    #pragma unroll
    for (int i = 0; i < 8; ++i) tmp[i] = f2bf(acc[g8 * 8 + i]);
    *(uint4*)&op[g8 * 8] = *(const uint4*)tmp;
  }
  __syncthreads();
  float* red = (float*)sp;
  red[tid] = s;
  red[256 + tid] = sq;
  __syncthreads();
  for (int o = 128; o > 0; o >>= 1) {
    if (tid < o) {
      red[tid] += red[tid + o];
      red[256 + tid] += red[256 + tid + o];
    }
    __syncthreads();
  }
  if (tid == 0) {
    atomicAdd(&bnacc[f], red[0]);
    atomicAdd(&bnacc[HID + f], red[256]);
  }
}

// K8: finalize BN stats, pre-folded with bn_g/bn_b:
// scaleA[f] = rstd*g, shiftB[f] = b - mu*scaleA  (y = x*scaleA + shiftB)
__global__ __launch_bounds__(256) void k8_fin(
    const float* __restrict__ bnacc, const float* __restrict__ g,
    const float* __restrict__ bia, float* __restrict__ scaleA,
    float* __restrict__ shiftB) {
  int f = threadIdx.x;
  float mu = bnacc[f] * (1.0f / 65536.f);
  float var = bnacc[HID + f] * (1.0f / 65536.f) - mu * mu;
  float sA = rsqrtf(var + 1e-5f) * g[f];
  scaleA[f] = sA;
  shiftB[f] = bia[f] - mu * sA;
}

// K10: out = gelu(gelu(bn(ym2))) @ w_p2 + b_p2 + xf via MFMA.
// BN+double-gelu fused into the B-fragment load (replaces k9_act + g2b
// roundtrip): each (b,f,p) element is consumed by exactly one lane
// (K-reduction is quad-split), so no duplicated erf work.
__global__ __launch_bounds__(256) void k10_p2(
    const bfu* __restrict__ ym2, const float* __restrict__ scaleA,
    const float* __restrict__ shiftB, const bfu* __restrict__ ap2,
    const float* __restrict__ bp2, const float* __restrict__ xf,
    float* __restrict__ outp) {
  int b = blockIdx.y;
  int ptile = blockIdx.x * 64;
  int tid = threadIdx.x;
  int wv = tid >> 6, lane = tid & 63;
  int quad = lane >> 4, n16 = lane & 15;
  int p = ptile + wv * 16 + n16;
  f32x4 acc[8];
  #pragma unroll
  for (int mt = 0; mt < 8; ++mt) acc[mt] = (f32x4){0.f, 0.f, 0.f, 0.f};
  #pragma unroll
  for (int ph = 0; ph < 8; ++ph) {
    int gg = ph * 4 + quad;
    const bfu* ymp = ym2 + (((size_t)(b * HID + gg * 8)) << 14) + p;
    float4 sa0 = *(const float4*)(scaleA + gg * 8);
    float4 sa1 = *(const float4*)(scaleA + gg * 8 + 4);
    float4 sb0 = *(const float4*)(shiftB + gg * 8);
    float4 sb1 = *(const float4*)(shiftB + gg * 8 + 4);
    float sav[8] = {sa0.x, sa0.y, sa0.z, sa0.w, sa1.x, sa1.y, sa1.z, sa1.w};
    float sbv[8] = {sb0.x, sb0.y, sb0.z, sb0.w, sb1.x, sb1.y, sb1.z, sb1.w};
    float vals[8];
    #pragma unroll
    for (int j = 0; j < 8; ++j) vals[j] = bf2f(ymp[(size_t)j << 14]);
    bfu frag[8];
    #pragma unroll
    for (int j = 0; j < 8; ++j) {
      float v = fmaf(vals[j], sav[j], sbv[j]);
      frag[j] = f2bf(gelu_exact(gelu_exact(v)));
    }
    bf16x8 bfrag = *(const bf16x8*)frag;
    const bfu* arow = ap2 + ((size_t)gg * 128 + n16) * 8;
    #pragma unroll
    for (int mt = 0; mt < 8; ++mt) {
      bf16x8 afrag = *(const bf16x8*)&arow[mt * 128];
      acc[mt] = __builtin_amdgcn_mfma_f32_16x16x32_bf16(afrag, bfrag, acc[mt], 0, 0, 0);
    }
  }
  #pragma unroll
  for (int mt = 0; mt < 8; ++mt) {
    #pragma unroll
    for (int r = 0; r < 4; ++r) {
      int c = mt * 16 + quad * 4 + r;
      size_t off = ((size_t)(b * DIMC + c) << 14) + p;
      outp[off] = acc[mt][r] + bp2[c] + xf[off];
    }
  }
}

extern "C" void kernel_launch(void* const* d_in, const int* in_sizes, int n_in,
                              void* d_out, int out_size, void* d_ws,
                              size_t ws_size, hipStream_t stream) {
  const float* x = (const float*)d_in[0];
  const float* ln1_g = (const float*)d_in[1];
  const float* ln1_b = (const float*)d_in[2];
  const float* w_qkv = (const float*)d_in[3];
  const float* w_out = (const float*)d_in[4];
  const float* b_out = (const float*)d_in[5];
  const float* ln2_g = (const float*)d_in[6];
  const float* ln2_b = (const float*)d_in[7];
  const float* w_p0 = (const float*)d_in[8];
  const float* b_p0 = (const float*)d_in[9];
  const float* dw_k = (const float*)d_in[10];
  const float* bn_g = (const float*)d_in[11];
  const float* bn_b = (const float*)d_in[12];
  const float* w_p2 = (const float*)d_in[13];
  const float* b_p2 = (const float*)d_in[14];
  float* outp = (float*)d_out;

  char* ws = (char*)d_ws;
  size_t off = 0;
  auto alloc = [&](size_t bytes) {
    void* p = ws + off;
    off += (bytes + 1023) & ~(size_t)1023;
    return p;
  };
  bfu* tok = (bfu*)alloc((size_t)NREG * DIMC * TT * 2);
  float* xf = (float*)alloc((size_t)BB * DIMC * HW * 4);
  bfu* xln = (bfu*)alloc((size_t)BB * DIMC * HW * 2);
  bfu* ym = (bfu*)alloc((size_t)BB * HID * HW * 2);
  bfu* ym2 = (bfu*)alloc((size_t)BB * HID * HW * 2);
  float* bnacc = (float*)alloc(2 * HID * 4);
  float* bnm = (float*)alloc(HID * 4);   // scaleA
  float* bnr = (float*)alloc(HID * 4);   // shiftB
  bfu* wqkvT = (bfu*)alloc(16 * 3072 * 2);
  bfu* ap0 = (bfu*)alloc(16 * 256 * 8 * 2);
  bfu* ap2 = (bfu*)alloc(32 * 128 * 8 * 2);
  bfu* awout = (bfu*)alloc(16 * 128 * 8 * 2);
  // overlays (lifetimes disjoint)
  bfu* o = ym;     // used k23->k4; ym written first in k6
  bfu* aln = ym2;  // used k1->k23; ym2 written first in k7

  kprep<<<65, 256, 0, stream>>>(w_qkv, w_p0, w_p2, w_out, wqkvT, ap0, ap2,
                                awout, bnacc);
  k1_gather<<<NREG, 256, 0, stream>>>(x, ln1_g, ln1_b, tok, aln);
  k23_fused<<<dim3(NREG, NHEADS), 256, 0, stream>>>(aln, wqkvT, o);
  k4_outproj<<<dim3(NREG, 4), 256, 0, stream>>>(o, awout, b_out, tok);
  k5_merge<<<dim3(HH_, BB), 512, 0, stream>>>(tok, ln2_g, ln2_b, xf, xln);
  k6_p0<<<dim3(256, BB), 256, 0, stream>>>(xln, ap0, b_p0, ym);
  k7_conv<<<BB * HID, 256, 0, stream>>>(ym, dw_k, ym2, bnacc);
  k8_fin<<<1, 256, 0, stream>>>(bnacc, bn_g, bn_b, bnm, bnr);
  k10_p2<<<dim3(256, BB), 256, 0, stream>>>(ym2, bnm, bnr, ap2, b_p2, xf,
                                            outp);
}

// Round 11
// 391.974 us; speedup vs baseline: 1.0054x; 1.0054x over previous
//
#include <hip/hip_runtime.h>

#define DIMC 128
#define NHEADS 4
#define HD 32
#define HID 256
#define BB 4
#define HH_ 128
#define WW_ 128
#define HW 16384
#define RS 16
#define STEP 14
#define NR 9
#define NREGB 81
#define NREG 324
#define TT 256

typedef unsigned short bfu;  // bf16 bits
typedef __attribute__((ext_vector_type(8))) short bf16x8;
typedef __attribute__((ext_vector_type(4))) float f32x4;

__device__ __forceinline__ float bf2f(bfu u) {
  return __uint_as_float(((unsigned int)u) << 16);
}
__device__ __forceinline__ bfu f2bf(float f) {
  unsigned int i = __float_as_uint(f);
  unsigned int r = i + 0x7fffu + ((i >> 16) & 1u);
  return (bfu)(r >> 16);
}
// HW packed f32->bf16 (RNE): dst.lo16 = bf16(lo), dst.hi16 = bf16(hi).
// Used ONLY in k23's V-scatter this round (bisection probe for semantics).
__device__ __forceinline__ unsigned cvt_pk_bf16(float lo, float hi) {
  unsigned r;
  asm("v_cvt_pk_bf16_f32 %0, %1, %2" : "=v"(r) : "v"(lo), "v"(hi));
  return r;
}
__device__ __forceinline__ float gelu_exact(float x) {
  return 0.5f * x * (1.0f + erff(x * 0.70710678118654752f));
}

// K1: gather -> tok bf16 [reg][c][t]; aln bf16 blocked [reg][g=c/8][t][8c]
// Blocks >= NREG run the weight-prep tail (former kprep, arithmetic
// byte-identical to the R0-verified kprep; NO scaling folds):
//  pb 0..23 wqkvT; pb 24 zero bnacc; pb 25..40 ap0; pb 41..56 ap2;
//  pb 57..64 awout
__global__ __launch_bounds__(256) void k1_gather(
    const float* __restrict__ x, const float* __restrict__ g,
    const float* __restrict__ bia, bfu* __restrict__ tok,
    bfu* __restrict__ aln, const float* __restrict__ wqkv,
    const float* __restrict__ wp0, const float* __restrict__ wp2,
    const float* __restrict__ wout, bfu* __restrict__ wqkvT,
    bfu* __restrict__ ap0, bfu* __restrict__ ap2, bfu* __restrict__ awout,
    float* __restrict__ bnacc) {
  int bid = blockIdx.x;
  int tid = threadIdx.x;
  if (bid >= NREG) {
    int pb = bid - NREG;
    if (pb < 24) {
      int task = pb * 256 + tid;  // kg*384 + n
      int kg = task / 384, n = task % 384;
      bfu tmp[8];
      #pragma unroll
      for (int j = 0; j < 8; ++j) tmp[j] = f2bf(wqkv[(kg * 8 + j) * 384 + n]);
      *(uint4*)&wqkvT[(size_t)kg * 3072 + n * 8] = *(const uint4*)tmp;
    } else if (pb == 24) {
      bnacc[tid] = 0.f;
      bnacc[256 + tid] = 0.f;
    } else if (pb < 41) {
      int task = (pb - 25) * 256 + tid;  // kg*256 + f
      int kg = task >> 8, f = task & 255;
      bfu tmp[8];
      #pragma unroll
      for (int j = 0; j < 8; ++j) tmp[j] = f2bf(wp0[(kg * 8 + j) * 256 + f]);
      *(uint4*)&ap0[((size_t)kg * 256 + f) * 8] = *(const uint4*)tmp;
    } else if (pb < 57) {
      int task = (pb - 41) * 256 + tid;  // kg*128 + c
      int kg = task >> 7, c = task & 127;
      bfu tmp[8];
      #pragma unroll
      for (int j = 0; j < 8; ++j) tmp[j] = f2bf(wp2[(kg * 8 + j) * 128 + c]);
      *(uint4*)&ap2[((size_t)kg * 128 + c) * 8] = *(const uint4*)tmp;
    } else {
      int task = (pb - 57) * 256 + tid;  // kg*128 + c
      int kg = task >> 7, c = task & 127;
      bfu tmp[8];
      #pragma unroll
      for (int j = 0; j < 8; ++j) tmp[j] = f2bf(wout[(kg * 8 + j) * 128 + c]);
      *(uint4*)&awout[((size_t)kg * 128 + c) * 8] = *(const uint4*)tmp;
    }
    return;
  }
  int reg = bid;
  int b = reg / NREGB, ij = reg % NREGB;
  int i = ij / NR, j = ij % NR;
  int t = tid;
  int r = t >> 4, s = t & 15;
  int hh = i * STEP + r, ww = j * STEP + s;
  const float* xp = x + (size_t)b * DIMC * HW + (size_t)hh * WW_ + ww;
  bfu* tp = tok + (size_t)reg * DIMC * TT + t;
  float sum = 0.f, sq = 0.f;
  #pragma unroll 4
  for (int c = 0; c < DIMC; ++c) {
    float v = xp[(size_t)c * HW];
    tp[c * TT] = f2bf(v);
    sum += v;
    sq = fmaf(v, v, sq);
  }
  float mu = sum * (1.0f / DIMC);
  float var = sq * (1.0f / DIMC) - mu * mu;
  float rstd = rsqrtf(var + 1e-5f);
  bfu* ap = aln + (size_t)reg * 32768 + t * 8;
  #pragma unroll
  for (int gidx = 0; gidx < 16; ++gidx) {
    bfu tmp[8];
    #pragma unroll
    for (int jj = 0; jj < 8; ++jj) {
      int c = gidx * 8 + jj;
      float vv = xp[(size_t)c * HW];  // L2-hot re-read
      tmp[jj] = f2bf((vv - mu) * rstd * g[c] + bia[c]);
    }
    *(uint4*)&ap[(size_t)gidx * 2048] = *(const uint4*)tmp;
  }
}

// K23: fused per-(region,head) QKV projection + attention.
// R0-VERIFIED body (6-tile single-pass GEMM, stride-40 sQ/sK, f2bf Q/K
// scatter, __expf softmax). Single delta this round: V-scatter uses
// cvt_pk_bf16 + uint2 LDS writes (semantics probe).
__global__ __launch_bounds__(256) void k23_fused(
    const bfu* __restrict__ aln, const bfu* __restrict__ wqkvT,
    bfu* __restrict__ o) {
  int reg = blockIdx.x;
  int h = blockIdx.y;
  __shared__ __align__(16) bfu sQ[256 * 40];        // [tok][d32 +8pad] 20.5KB
  __shared__ __align__(16) bfu sK[256 * 40];        // 20.5KB
  __shared__ __align__(16) bfu vperm[8 * 4 * 264];  // 16.9KB
  int tid = threadIdx.x;
  int wave = tid >> 6, lane = tid & 63;
  int quad = lane >> 4, n16 = lane & 15;

  // ---- QKV GEMM for this head: [256 tok x 96 cols] = aln @ W[:, cols(h)]
  const bfu* ab = aln + (size_t)reg * 32768 + (wave * 64 + n16) * 8;
  int colb[6];
  colb[0] = h * 32;        // q lo
  colb[1] = h * 32 + 16;   // q hi
  colb[2] = 128 + h * 32;  // k lo
  colb[3] = 144 + h * 32;  // k hi
  colb[4] = 256 + h * 32;  // v lo
  colb[5] = 272 + h * 32;  // v hi
  f32x4 acc[4][6];
  #pragma unroll
  for (int m = 0; m < 4; ++m)
    #pragma unroll
    for (int nt = 0; nt < 6; ++nt) acc[m][nt] = (f32x4){0.f, 0.f, 0.f, 0.f};
  #pragma unroll
  for (int ph = 0; ph < 4; ++ph) {
    int gg = ph * 4 + quad;
    bf16x8 af[4];
    #pragma unroll
    for (int m = 0; m < 4; ++m)
      af[m] = *(const bf16x8*)&ab[(size_t)gg * 2048 + m * 128];
    const bfu* bgg = wqkvT + (size_t)gg * 3072;
    bf16x8 bfr[6];
    #pragma unroll
    for (int nt = 0; nt < 6; ++nt)
      bfr[nt] = *(const bf16x8*)&bgg[(colb[nt] + n16) * 8];
    #pragma unroll
    for (int m = 0; m < 4; ++m)
      #pragma unroll
      for (int nt = 0; nt < 6; ++nt)
        acc[m][nt] =
            __builtin_amdgcn_mfma_f32_16x16x32_bf16(af[m], bfr[nt], acc[m][nt], 0, 0, 0);
  }
  // ---- scatter acc -> LDS (C/D map: row = quad*4+r, col = n16)
  // token t = wave*64 + m*16 + quad*4 + r
  #pragma unroll
  for (int m = 0; m < 4; ++m) {
    int g = wave * 2 + (m >> 1);
    int jt = (m & 1) * 4;
    #pragma unroll
    for (int r = 0; r < 4; ++r) {
      int t = wave * 64 + m * 16 + quad * 4 + r;
      sQ[t * 40 + n16] = f2bf(acc[m][0][r]);
      sQ[t * 40 + 16 + n16] = f2bf(acc[m][1][r]);
      sK[t * 40 + n16] = f2bf(acc[m][2][r]);
      sK[t * 40 + 16 + n16] = f2bf(acc[m][3][r]);
    }
    // V-scatter probe: pack 4 token-slots (r=0..3) per column with cvt_pk,
    // write as two b64s. Element map identical to R0's per-element scatter:
    // vperm[(g*4+quad)*264 + jt + r + d*8] = V[t][d]
    unsigned v0 = cvt_pk_bf16(acc[m][4][0], acc[m][4][1]);
    unsigned v1 = cvt_pk_bf16(acc[m][4][2], acc[m][4][3]);
    unsigned v2 = cvt_pk_bf16(acc[m][5][0], acc[m][5][1]);
    unsigned v3 = cvt_pk_bf16(acc[m][5][2], acc[m][5][3]);
    int vbase = (g * 4 + quad) * 264 + jt;
    *(uint2*)&vperm[vbase + n16 * 8] = make_uint2(v0, v1);
    *(uint2*)&vperm[vbase + (16 + n16) * 8] = make_uint2(v2, v3);
  }
  __syncthreads();

  // ---- attention (R0-verified body) ----
  const f32x4 zero = {0.f, 0.f, 0.f, 0.f};
  const float scale = 0.17677669529663687f;  // 1/sqrt(32)
  for (int mi = 0; mi < 4; ++mi) {
    int mt = wave * 4 + mi;
    bf16x8 qf = *(const bf16x8*)&sQ[(mt * 16 + n16) * 40 + quad * 8];
    f32x4 st[16];
    #pragma unroll
    for (int T = 0; T < 16; ++T) {
      bf16x8 kf = *(const bf16x8*)&sK[(T * 16 + n16) * 40 + quad * 8];
      st[T] = __builtin_amdgcn_mfma_f32_16x16x32_bf16(kf, qf, zero, 0, 0, 0);
    }
    float m = st[0][0];
    #pragma unroll
    for (int T = 0; T < 16; ++T)
      #pragma unroll
      for (int r = 0; r < 4; ++r) m = fmaxf(m, st[T][r]);
    m = fmaxf(m, __shfl_xor(m, 16, 64));
    m = fmaxf(m, __shfl_xor(m, 32, 64));
    float l = 0.f;
    #pragma unroll
    for (int T = 0; T < 16; ++T)
      #pragma unroll
      for (int r = 0; r < 4; ++r) {
        float p = __expf((st[T][r] - m) * scale);
        st[T][r] = p;
        l += p;
      }
    l += __shfl_xor(l, 16, 64);
    l += __shfl_xor(l, 32, 64);
    float inv = 1.0f / l;
    f32x4 oa0 = zero, oa1 = zero;
    #pragma unroll
    for (int g = 0; g < 8; ++g) {
      bfu pk[8];
      #pragma unroll
      for (int r = 0; r < 4; ++r) {
        pk[r] = f2bf(st[2 * g][r]);
        pk[4 + r] = f2bf(st[2 * g + 1][r]);
      }
      bf16x8 pf = *(const bf16x8*)pk;
      bf16x8 va = *(const bf16x8*)&vperm[(g * 4 + quad) * 264 + n16 * 8];
      bf16x8 vb = *(const bf16x8*)&vperm[(g * 4 + quad) * 264 + (16 + n16) * 8];
      oa0 = __builtin_amdgcn_mfma_f32_16x16x32_bf16(va, pf, oa0, 0, 0, 0);
      oa1 = __builtin_amdgcn_mfma_f32_16x16x32_bf16(vb, pf, oa1, 0, 0, 0);
    }
    bfu* ob = o + ((size_t)reg * 256 + mt * 16 + n16) * 128 + h * 32 + quad * 4;
    ushort4 s0, s1;
    s0.x = f2bf(oa0[0] * inv);
    s0.y = f2bf(oa0[1] * inv);
    s0.z = f2bf(oa0[2] * inv);
    s0.w = f2bf(oa0[3] * inv);
    s1.x = f2bf(oa1[0] * inv);
    s1.y = f2bf(oa1[1] * inv);
    s1.z = f2bf(oa1[2] * inv);
    s1.w = f2bf(oa1[3] * inv);
    *(ushort4*)&ob[0] = s0;
    *(ushort4*)&ob[16] = s1;
  }
}

// K4: tok[c][t] (bf16) += o @ w_out + b_out via MFMA, LDS-free
__global__ __launch_bounds__(256) void k4_outproj(
    const bfu* __restrict__ o, const bfu* __restrict__ awout,
    const float* __restrict__ bout, bfu* __restrict__ tok) {
  int reg = blockIdx.x;
  int tt = blockIdx.y;
  int tid = threadIdx.x;
  int wave = tid >> 6, lane = tid & 63;
  int quad = lane >> 4, n16 = lane & 15;
  int t = tt * 64 + wave * 16 + n16;
  const bfu* ob = o + ((size_t)reg * 256 + t) * 128;
  f32x4 acc[8];
  #pragma unroll
  for (int mt = 0; mt < 8; ++mt) acc[mt] = (f32x4){0.f, 0.f, 0.f, 0.f};
  #pragma unroll
  for (int kt = 0; kt < 4; ++kt) {
    bf16x8 bfrag = *(const bf16x8*)&ob[kt * 32 + quad * 8];
    const bfu* arow = awout + ((size_t)(kt * 4 + quad) * 128 + n16) * 8;
    #pragma unroll
    for (int mt = 0; mt < 8; ++mt) {
      bf16x8 afrag = *(const bf16x8*)&arow[mt * 128];
      acc[mt] = __builtin_amdgcn_mfma_f32_16x16x32_bf16(afrag, bfrag, acc[mt], 0, 0, 0);
    }
  }
  bfu* tokr = tok + (size_t)reg * DIMC * TT + t;
  #pragma unroll
  for (int mt = 0; mt < 8; ++mt) {
    #pragma unroll
    for (int r = 0; r < 4; ++r) {
      int c = mt * 16 + quad * 4 + r;
      float val = bf2f(tokr[c * TT]) + acc[mt][r] + bout[c];
      tokr[c * TT] = f2bf(val);
    }
  }
}

// K5: overlap merge (bf16 tok) -> xf fp32 + xln bf16 blocked [b][cg][p][8c]
__global__ __launch_bounds__(512) void k5_merge(
    const bfu* __restrict__ tok, const float* __restrict__ ln2g,
    const float* __restrict__ ln2b, float* __restrict__ xf,
    bfu* __restrict__ xln) {
  int hh = blockIdx.x, b = blockIdx.y;
  int tid = threadIdx.x;
  int w = tid & 127, q = tid >> 7;
  int ilo = (hh >= 2) ? (hh - 2) / 14 : 0;
  int ihi = hh / 14;
  if (ihi > 8) ihi = 8;
  int jlo = (w >= 2) ? (w - 2) / 14 : 0;
  int jhi = w / 14;
  if (jhi > 8) jhi = 8;
  float rcnt = 1.0f / (float)((ihi - ilo + 1) * (jhi - jlo + 1));
  size_t offs[4];
  int nij = 0;
  for (int i = ilo; i <= ihi; ++i)
    for (int j = jlo; j <= jhi; ++j) {
      int reg = b * NREGB + i * NR + j;
      int r = hh - i * STEP, s = w - j * STEP;
      offs[nij++] = (size_t)reg * DIMC * TT + r * 16 + s;
    }
  float* xp = xf + ((size_t)b * DIMC << 14) + hh * WW_ + w;
  float mm[32];
  float sum = 0.f, sq = 0.f;
  int c0 = q * 32;
  for (int cc = 0; cc < 32; ++cc) {
    int c = c0 + cc;
    float s = 0.f;
    for (int k = 0; k < nij; ++k) s += bf2f(tok[offs[k] + c * TT]);
    float m = s * rcnt;
    xp[(size_t)c << 14] = m;
    mm[cc] = m;
    sum += m;
    sq = fmaf(m, m, sq);
  }
  __shared__ float rs[512];
  __shared__ float rq[512];
  __shared__ float muS[128];
  __shared__ float rsdS[128];
  rs[tid] = sum;
  rq[tid] = sq;
  __syncthreads();
  if (tid < 128) {
    float s4 = rs[tid] + rs[tid + 128] + rs[tid + 256] + rs[tid + 384];
    float q4 = rq[tid] + rq[tid + 128] + rq[tid + 256] + rq[tid + 384];
    float mu = s4 * (1.0f / DIMC);
    float var = q4 * (1.0f / DIMC) - mu * mu;
    muS[tid] = mu;
    rsdS[tid] = rsqrtf(var + 1e-5f);
  }
  __syncthreads();
  float mu = muS[w], rstd = rsdS[w];
  int p = hh * WW_ + w;
  #pragma unroll
  for (int gl = 0; gl < 4; ++gl) {
    int gidx = q * 4 + gl;
    bfu tmp[8];
    #pragma unroll
    for (int j = 0; j < 8; ++j) {
      int c = gidx * 8 + j;
      tmp[j] = f2bf((mm[gl * 8 + j] - mu) * rstd * ln2g[c] + ln2b[c]);
    }
    *(uint4*)&xln[(((size_t)(b * 16 + gidx) << 14) + p) * 8] = *(const uint4*)tmp;
  }
}

// K6: ym[b][f][p] = xln @ w_p0 + b_p0 via MFMA
__global__ __launch_bounds__(256) void k6_p0(
    const bfu* __restrict__ xln, const bfu* __restrict__ ap0,
    const float* __restrict__ bp0, bfu* __restrict__ ym) {
  int b = blockIdx.y;
  int ptile = blockIdx.x * 64;
  int tid = threadIdx.x;
  int wv = tid >> 6, lane = tid & 63;
  int quad = lane >> 4, n16 = lane & 15;
  int p = ptile + wv * 16 + n16;
  f32x4 acc[16];
  #pragma unroll
  for (int mt = 0; mt < 16; ++mt) acc[mt] = (f32x4){0.f, 0.f, 0.f, 0.f};
  #pragma unroll
  for (int ph = 0; ph < 4; ++ph) {
    int gg = ph * 4 + quad;
    bf16x8 bfrag = *(const bf16x8*)&xln[(((size_t)(b * 16 + gg) << 14) + p) * 8];
    const bfu* arow = ap0 + ((size_t)gg * 256 + n16) * 8;
    #pragma unroll
    for (int mt = 0; mt < 16; ++mt) {
      bf16x8 afrag = *(const bf16x8*)&arow[mt * 128];
      acc[mt] = __builtin_amdgcn_mfma_f32_16x16x32_bf16(afrag, bfrag, acc[mt], 0, 0, 0);
    }
  }
  #pragma unroll
  for (int mt = 0; mt < 16; ++mt) {
    #pragma unroll
    for (int r = 0; r < 4; ++r) {
      int f = mt * 16 + quad * 4 + r;
      ym[((size_t)(b * HID + f) << 14) + p] = f2bf(acc[mt][r] + bp0[f]);
    }
  }
}

// K7: 5x5 depthwise conv, whole plane in LDS, fused BN partials
__global__ __launch_bounds__(256) void k7_conv(
    const bfu* __restrict__ ym, const float* __restrict__ dwk,
    bfu* __restrict__ ym2, float* __restrict__ bnacc) {
  int bf = blockIdx.x;
  int f = bf & (HID - 1);
  __shared__ bfu sp[128 * 134];
  const bfu* in = ym + ((size_t)bf << 14);
  int tid = threadIdx.x;
  for (int idx = tid; idx < 2048; idx += 256) {
    int r = idx >> 4, c8 = (idx & 15) << 3;
    ushort4 a = *(const ushort4*)&in[(r << 7) + c8];
    ushort4 b = *(const ushort4*)&in[(r << 7) + c8 + 4];
    bfu* d = &sp[r * 134 + c8];
    d[0] = a.x; d[1] = a.y; d[2] = a.z; d[3] = a.w;
    d[4] = b.x; d[5] = b.y; d[6] = b.z; d[7] = b.w;
  }
  float wk[25];
  #pragma unroll
  for (int i = 0; i < 25; ++i) wk[i] = dwk[f * 25 + i];
  __syncthreads();
  int row = tid >> 1, half = (tid & 1) << 6;
  float acc[64];
  #pragma unroll
  for (int i = 0; i < 64; ++i) acc[i] = 0.f;
  #pragma unroll
  for (int ky = 0; ky < 5; ++ky) {
    int y = row + ky - 2;
    if (y < 0 || y >= 128) continue;
    const bfu* rp = &sp[y * 134];
    float win[68];
    #pragma unroll
    for (int c = 0; c < 68; ++c) {
      int cc = half + c - 2;
      win[c] = (cc >= 0 && cc < 128) ? bf2f(rp[cc]) : 0.f;
    }
    #pragma unroll
    for (int kx = 0; kx < 5; ++kx) {
      float wv = wk[ky * 5 + kx];
      #pragma unroll
      for (int i = 0; i < 64; ++i) acc[i] = fmaf(win[i + kx], wv, acc[i]);
    }
  }
  float s = 0.f, sq = 0.f;
  #pragma unroll
  for (int i = 0; i < 64; ++i) {
    s += acc[i];
    sq = fmaf(acc[i], acc[i], sq);
  }
  bfu* op = ym2 + ((size_t)bf << 14) + (row << 7) + half;
  #pragma unroll
  for (int g8 = 0; g8 < 8; ++g8) {
    bfu tmp[8];
    #pragma unroll
    for (int i = 0; i < 8; ++i) tmp[i] = f2bf(acc[g8 * 8 + i]);
    *(uint4*)&op[g8 * 8] = *(const uint4*)tmp;
  }
  __syncthreads();
  float* red = (float*)sp;
  red[tid] = s;
  red[256 + tid] = sq;
  __syncthreads();
  for (int o = 128; o > 0; o >>= 1) {
    if (tid < o) {
      red[tid] += red[tid + o];
      red[256 + tid] += red[256 + tid + o];
    }
    __syncthreads();
  }
  if (tid == 0) {
    atomicAdd(&bnacc[f], red[0]);
    atomicAdd(&bnacc[HID + f], red[256]);
  }
}

// K10: out = gelu(gelu(bn(ym2))) @ w_p2 + b_p2 + xf via MFMA.
// BN finalize (former k8) folded into a block prologue: 256 threads compute
// scale/shift from bnacc into LDS, then broadcast-read per fragment.
__global__ __launch_bounds__(256) void k10_p2(
    const bfu* __restrict__ ym2, const float* __restrict__ bnacc,
    const float* __restrict__ bng, const float* __restrict__ bnb,
    const bfu* __restrict__ ap2, const float* __restrict__ bp2,
    const float* __restrict__ xf, float* __restrict__ outp) {
  int b = blockIdx.y;
  int ptile = blockIdx.x * 64;
  int tid = threadIdx.x;
  __shared__ float sA[HID];
  __shared__ float sB[HID];
  {
    float mu = bnacc[tid] * (1.0f / 65536.f);
    float var = bnacc[HID + tid] * (1.0f / 65536.f) - mu * mu;
    float sa = rsqrtf(var + 1e-5f) * bng[tid];
    sA[tid] = sa;
    sB[tid] = bnb[tid] - mu * sa;
  }
  __syncthreads();
  int wv = tid >> 6, lane = tid & 63;
  int quad = lane >> 4, n16 = lane & 15;
  int p = ptile + wv * 16 + n16;
  f32x4 acc[8];
  #pragma unroll
  for (int mt = 0; mt < 8; ++mt) acc[mt] = (f32x4){0.f, 0.f, 0.f, 0.f};
  #pragma unroll
  for (int ph = 0; ph < 8; ++ph) {
    int gg = ph * 4 + quad;
    const bfu* ymp = ym2 + (((size_t)(b * HID + gg * 8)) << 14) + p;
    float vals[8];
    #pragma unroll
    for (int j = 0; j < 8; ++j) vals[j] = bf2f(ymp[(size_t)j << 14]);
    bfu frag[8];
    #pragma unroll
    for (int j = 0; j < 8; ++j) {
      float v = fmaf(vals[j], sA[gg * 8 + j], sB[gg * 8 + j]);
      frag[j] = f2bf(gelu_exact(gelu_exact(v)));
    }
    bf16x8 bfrag = *(const bf16x8*)frag;
    const bfu* arow = ap2 + ((size_t)gg * 128 + n16) * 8;
    #pragma unroll
    for (int mt = 0; mt < 8; ++mt) {
      bf16x8 afrag = *(const bf16x8*)&arow[mt * 128];
      acc[mt] = __builtin_amdgcn_mfma_f32_16x16x32_bf16(afrag, bfrag, acc[mt], 0, 0, 0);
    }
  }
  #pragma unroll
  for (int mt = 0; mt < 8; ++mt) {
    #pragma unroll
    for (int r = 0; r < 4; ++r) {
      int c = mt * 16 + quad * 4 + r;
      size_t off = ((size_t)(b * DIMC + c) << 14) + p;
      outp[off] = acc[mt][r] + bp2[c] + xf[off];
    }
  }
}

extern "C" void kernel_launch(void* const* d_in, const int* in_sizes, int n_in,
                              void* d_out, int out_size, void* d_ws,
                              size_t ws_size, hipStream_t stream) {
  const float* x = (const float*)d_in[0];
  const float* ln1_g = (const float*)d_in[1];
  const float* ln1_b = (const float*)d_in[2];
  const float* w_qkv = (const float*)d_in[3];
  const float* w_out = (const float*)d_in[4];
  const float* b_out = (const float*)d_in[5];
  const float* ln2_g = (const float*)d_in[6];
  const float* ln2_b = (const float*)d_in[7];
  const float* w_p0 = (const float*)d_in[8];
  const float* b_p0 = (const float*)d_in[9];
  const float* dw_k = (const float*)d_in[10];
  const float* bn_g = (const float*)d_in[11];
  const float* bn_b = (const float*)d_in[12];
  const float* w_p2 = (const float*)d_in[13];
  const float* b_p2 = (const float*)d_in[14];
  float* outp = (float*)d_out;

  char* ws = (char*)d_ws;
  size_t off = 0;
  auto alloc = [&](size_t bytes) {
    void* p = ws + off;
    off += (bytes + 1023) & ~(size_t)1023;
    return p;
  };
  bfu* tok = (bfu*)alloc((size_t)NREG * DIMC * TT * 2);
  float* xf = (float*)alloc((size_t)BB * DIMC * HW * 4);
  bfu* xln = (bfu*)alloc((size_t)BB * DIMC * HW * 2);
  bfu* ym = (bfu*)alloc((size_t)BB * HID * HW * 2);
  bfu* ym2 = (bfu*)alloc((size_t)BB * HID * HW * 2);
  float* bnacc = (float*)alloc(2 * HID * 4);
  bfu* wqkvT = (bfu*)alloc(16 * 3072 * 2);
  bfu* ap0 = (bfu*)alloc(16 * 256 * 8 * 2);
  bfu* ap2 = (bfu*)alloc(32 * 128 * 8 * 2);
  bfu* awout = (bfu*)alloc(16 * 128 * 8 * 2);
  // overlays (lifetimes disjoint)
  bfu* o = ym;     // used k23->k4; ym written first in k6
  bfu* aln = ym2;  // used k1->k23; ym2 written first in k7

  // k1 grid: NREG gather blocks + 65 weight-prep blocks (former kprep)
  k1_gather<<<NREG + 65, 256, 0, stream>>>(x, ln1_g, ln1_b, tok, aln, w_qkv,
                                           w_p0, w_p2, w_out, wqkvT, ap0, ap2,
                                           awout, bnacc);
  k23_fused<<<dim3(NREG, NHEADS), 256, 0, stream>>>(aln, wqkvT, o);
  k4_outproj<<<dim3(NREG, 4), 256, 0, stream>>>(o, awout, b_out, tok);
  k5_merge<<<dim3(HH_, BB), 512, 0, stream>>>(tok, ln2_g, ln2_b, xf, xln);
  k6_p0<<<dim3(256, BB), 256, 0, stream>>>(xln, ap0, b_p0, ym);
  k7_conv<<<BB * HID, 256, 0, stream>>>(ym, dw_k, ym2, bnacc);
  k10_p2<<<dim3(256, BB), 256, 0, stream>>>(ym2, bnacc, bn_g, bn_b, ap2, b_p2,
                                            xf, outp);
}

// Round 12
// 351.492 us; speedup vs baseline: 1.1212x; 1.1152x over previous
//
#include <hip/hip_runtime.h>

#define DIMC 128
#define NHEADS 4
#define HD 32
#define HID 256
#define BB 4
#define HH_ 128
#define WW_ 128
#define HW 16384
#define RS 16
#define STEP 14
#define NR 9
#define NREGB 81
#define NREG 324
#define TT 256

typedef unsigned short bfu;  // bf16 bits
typedef __attribute__((ext_vector_type(8))) short bf16x8;
typedef __attribute__((ext_vector_type(4))) float f32x4;

__device__ __forceinline__ float bf2f(bfu u) {
  return __uint_as_float(((unsigned int)u) << 16);
}
// HW packed f32->bf16 (RNE): dst.lo16 = bf16(lo), dst.hi16 = bf16(hi).
// Semantics hardware-verified R11 (V-scatter probe, absmax == software path).
__device__ __forceinline__ unsigned cvt_pk_bf16(float lo, float hi) {
  unsigned r;
  asm("v_cvt_pk_bf16_f32 %0, %1, %2" : "=v"(r) : "v"(lo), "v"(hi));
  return r;
}
__device__ __forceinline__ float gelu_exact(float x) {
  return 0.5f * x * (1.0f + erff(x * 0.70710678118654752f));
}

// K1: gather -> tok bf16 [reg][c][t]; aln bf16 blocked [reg][g=c/8][t][8c]
// Blocks >= NREG run the weight-prep tail:
//  pb 0..23 wqkvT; pb 24 zero bnacc; pb 25..40 ap0; pb 41..56 ap2;
//  pb 57..64 awout
__global__ __launch_bounds__(256) void k1_gather(
    const float* __restrict__ x, const float* __restrict__ g,
    const float* __restrict__ bia, bfu* __restrict__ tok,
    bfu* __restrict__ aln, const float* __restrict__ wqkv,
    const float* __restrict__ wp0, const float* __restrict__ wp2,
    const float* __restrict__ wout, bfu* __restrict__ wqkvT,
    bfu* __restrict__ ap0, bfu* __restrict__ ap2, bfu* __restrict__ awout,
    float* __restrict__ bnacc) {
  int bid = blockIdx.x;
  int tid = threadIdx.x;
  if (bid >= NREG) {
    int pb = bid - NREG;
    if (pb < 24) {
      int task = pb * 256 + tid;  // kg*384 + n
      int kg = task / 384, n = task % 384;
      float v[8];
      #pragma unroll
      for (int j = 0; j < 8; ++j) v[j] = wqkv[(kg * 8 + j) * 384 + n];
      uint4 pk = make_uint4(cvt_pk_bf16(v[0], v[1]), cvt_pk_bf16(v[2], v[3]),
                            cvt_pk_bf16(v[4], v[5]), cvt_pk_bf16(v[6], v[7]));
      *(uint4*)&wqkvT[(size_t)kg * 3072 + n * 8] = pk;
    } else if (pb == 24) {
      bnacc[tid] = 0.f;
      bnacc[256 + tid] = 0.f;
    } else if (pb < 41) {
      int task = (pb - 25) * 256 + tid;  // kg*256 + f
      int kg = task >> 8, f = task & 255;
      float v[8];
      #pragma unroll
      for (int j = 0; j < 8; ++j) v[j] = wp0[(kg * 8 + j) * 256 + f];
      uint4 pk = make_uint4(cvt_pk_bf16(v[0], v[1]), cvt_pk_bf16(v[2], v[3]),
                            cvt_pk_bf16(v[4], v[5]), cvt_pk_bf16(v[6], v[7]));
      *(uint4*)&ap0[((size_t)kg * 256 + f) * 8] = pk;
    } else if (pb < 57) {
      int task = (pb - 41) * 256 + tid;  // kg*128 + c
      int kg = task >> 7, c = task & 127;
      float v[8];
      #pragma unroll
      for (int j = 0; j < 8; ++j) v[j] = wp2[(kg * 8 + j) * 128 + c];
      uint4 pk = make_uint4(cvt_pk_bf16(v[0], v[1]), cvt_pk_bf16(v[2], v[3]),
                            cvt_pk_bf16(v[4], v[5]), cvt_pk_bf16(v[6], v[7]));
      *(uint4*)&ap2[((size_t)kg * 128 + c) * 8] = pk;
    } else {
      int task = (pb - 57) * 256 + tid;  // kg*128 + c
      int kg = task >> 7, c = task & 127;
      float v[8];
      #pragma unroll
      for (int j = 0; j < 8; ++j) v[j] = wout[(kg * 8 + j) * 128 + c];
      uint4 pk = make_uint4(cvt_pk_bf16(v[0], v[1]), cvt_pk_bf16(v[2], v[3]),
                            cvt_pk_bf16(v[4], v[5]), cvt_pk_bf16(v[6], v[7]));
      *(uint4*)&awout[((size_t)kg * 128 + c) * 8] = pk;
    }
    return;
  }
  int reg = bid;
  int b = reg / NREGB, ij = reg % NREGB;
  int i = ij / NR, j = ij % NR;
  int t = tid;
  int r = t >> 4, s = t & 15;
  int hh = i * STEP + r, ww = j * STEP + s;
  const float* xp = x + (size_t)b * DIMC * HW + (size_t)hh * WW_ + ww;
  bfu* tp = tok + (size_t)reg * DIMC * TT + t;
  float sum = 0.f, sq = 0.f;
  #pragma unroll 4
  for (int c = 0; c < DIMC; c += 2) {
    float v0 = xp[(size_t)c * HW];
    float v1 = xp[(size_t)(c + 1) * HW];
    unsigned pk = cvt_pk_bf16(v0, v1);
    tp[c * TT] = (bfu)pk;
    tp[(c + 1) * TT] = (bfu)(pk >> 16);
    sum += v0 + v1;
    sq = fmaf(v0, v0, sq);
    sq = fmaf(v1, v1, sq);
  }
  float mu = sum * (1.0f / DIMC);
  float var = sq * (1.0f / DIMC) - mu * mu;
  float rstd = rsqrtf(var + 1e-5f);
  bfu* ap = aln + (size_t)reg * 32768 + t * 8;
  #pragma unroll
  for (int gidx = 0; gidx < 16; ++gidx) {
    float y[8];
    #pragma unroll
    for (int jj = 0; jj < 8; ++jj) {
      int c = gidx * 8 + jj;
      float vv = xp[(size_t)c * HW];  // L2-hot re-read
      y[jj] = (vv - mu) * rstd * g[c] + bia[c];
    }
    uint4 pk = make_uint4(cvt_pk_bf16(y[0], y[1]), cvt_pk_bf16(y[2], y[3]),
                          cvt_pk_bf16(y[4], y[5]), cvt_pk_bf16(y[6], y[7]));
    *(uint4*)&ap[(size_t)gidx * 2048] = pk;
  }
}

// K23: fused per-(region,head) QKV projection + attention.
// R11-verified structure; all pack sites now use cvt_pk (verified semantics).
__global__ __launch_bounds__(256) void k23_fused(
    const bfu* __restrict__ aln, const bfu* __restrict__ wqkvT,
    bfu* __restrict__ o) {
  int reg = blockIdx.x;
  int h = blockIdx.y;
  __shared__ __align__(16) bfu sQ[256 * 40];        // [tok][d32 +8pad] 20.5KB
  __shared__ __align__(16) bfu sK[256 * 40];        // 20.5KB
  __shared__ __align__(16) bfu vperm[8 * 4 * 264];  // 16.9KB
  int tid = threadIdx.x;
  int wave = tid >> 6, lane = tid & 63;
  int quad = lane >> 4, n16 = lane & 15;

  // ---- QKV GEMM for this head: [256 tok x 96 cols] = aln @ W[:, cols(h)]
  const bfu* ab = aln + (size_t)reg * 32768 + (wave * 64 + n16) * 8;
  int colb[6];
  colb[0] = h * 32;        // q lo
  colb[1] = h * 32 + 16;   // q hi
  colb[2] = 128 + h * 32;  // k lo
  colb[3] = 144 + h * 32;  // k hi
  colb[4] = 256 + h * 32;  // v lo
  colb[5] = 272 + h * 32;  // v hi
  f32x4 acc[4][6];
  #pragma unroll
  for (int m = 0; m < 4; ++m)
    #pragma unroll
    for (int nt = 0; nt < 6; ++nt) acc[m][nt] = (f32x4){0.f, 0.f, 0.f, 0.f};
  #pragma unroll
  for (int ph = 0; ph < 4; ++ph) {
    int gg = ph * 4 + quad;
    bf16x8 af[4];
    #pragma unroll
    for (int m = 0; m < 4; ++m)
      af[m] = *(const bf16x8*)&ab[(size_t)gg * 2048 + m * 128];
    const bfu* bgg = wqkvT + (size_t)gg * 3072;
    bf16x8 bfr[6];
    #pragma unroll
    for (int nt = 0; nt < 6; ++nt)
      bfr[nt] = *(const bf16x8*)&bgg[(colb[nt] + n16) * 8];
    #pragma unroll
    for (int m = 0; m < 4; ++m)
      #pragma unroll
      for (int nt = 0; nt < 6; ++nt)
        acc[m][nt] =
            __builtin_amdgcn_mfma_f32_16x16x32_bf16(af[m], bfr[nt], acc[m][nt], 0, 0, 0);
  }
  // ---- scatter acc -> LDS (C/D map: row = quad*4+r, col = n16)
  // token t = wave*64 + m*16 + quad*4 + r; addressing identical to R11.
  #pragma unroll
  for (int m = 0; m < 4; ++m) {
    int g = wave * 2 + (m >> 1);
    int jt = (m & 1) * 4;
    int T0 = wave * 64 + m * 16 + quad * 4;
    // Q/K: pack pairs (r, r+1), store halves (d16 / d16_hi)
    unsigned q00 = cvt_pk_bf16(acc[m][0][0], acc[m][0][1]);
    unsigned q01 = cvt_pk_bf16(acc[m][0][2], acc[m][0][3]);
    unsigned q10 = cvt_pk_bf16(acc[m][1][0], acc[m][1][1]);
    unsigned q11 = cvt_pk_bf16(acc[m][1][2], acc[m][1][3]);
    unsigned k00 = cvt_pk_bf16(acc[m][2][0], acc[m][2][1]);
    unsigned k01 = cvt_pk_bf16(acc[m][2][2], acc[m][2][3]);
    unsigned k10 = cvt_pk_bf16(acc[m][3][0], acc[m][3][1]);
    unsigned k11 = cvt_pk_bf16(acc[m][3][2], acc[m][3][3]);
    sQ[(T0 + 0) * 40 + n16] = (bfu)q00;
    sQ[(T0 + 1) * 40 + n16] = (bfu)(q00 >> 16);
    sQ[(T0 + 2) * 40 + n16] = (bfu)q01;
    sQ[(T0 + 3) * 40 + n16] = (bfu)(q01 >> 16);
    sQ[(T0 + 0) * 40 + 16 + n16] = (bfu)q10;
    sQ[(T0 + 1) * 40 + 16 + n16] = (bfu)(q10 >> 16);
    sQ[(T0 + 2) * 40 + 16 + n16] = (bfu)q11;
    sQ[(T0 + 3) * 40 + 16 + n16] = (bfu)(q11 >> 16);
    sK[(T0 + 0) * 40 + n16] = (bfu)k00;
    sK[(T0 + 1) * 40 + n16] = (bfu)(k00 >> 16);
    sK[(T0 + 2) * 40 + n16] = (bfu)k01;
    sK[(T0 + 3) * 40 + n16] = (bfu)(k01 >> 16);
    sK[(T0 + 0) * 40 + 16 + n16] = (bfu)k10;
    sK[(T0 + 1) * 40 + 16 + n16] = (bfu)(k10 >> 16);
    sK[(T0 + 2) * 40 + 16 + n16] = (bfu)k11;
    sK[(T0 + 3) * 40 + 16 + n16] = (bfu)(k11 >> 16);
    // V: verified uint2 path (R11 probe)
    unsigned v0 = cvt_pk_bf16(acc[m][4][0], acc[m][4][1]);
    unsigned v1 = cvt_pk_bf16(acc[m][4][2], acc[m][4][3]);
    unsigned v2 = cvt_pk_bf16(acc[m][5][0], acc[m][5][1]);
    unsigned v3 = cvt_pk_bf16(acc[m][5][2], acc[m][5][3]);
    int vbase = (g * 4 + quad) * 264 + jt;
    *(uint2*)&vperm[vbase + n16 * 8] = make_uint2(v0, v1);
    *(uint2*)&vperm[vbase + (16 + n16) * 8] = make_uint2(v2, v3);
  }
  __syncthreads();

  // ---- attention (R11-verified body; P-pack + O-store via cvt_pk) ----
  const f32x4 zero = {0.f, 0.f, 0.f, 0.f};
  const float scale = 0.17677669529663687f;  // 1/sqrt(32)
  for (int mi = 0; mi < 4; ++mi) {
    int mt = wave * 4 + mi;
    bf16x8 qf = *(const bf16x8*)&sQ[(mt * 16 + n16) * 40 + quad * 8];
    f32x4 st[16];
    #pragma unroll
    for (int T = 0; T < 16; ++T) {
      bf16x8 kf = *(const bf16x8*)&sK[(T * 16 + n16) * 40 + quad * 8];
      st[T] = __builtin_amdgcn_mfma_f32_16x16x32_bf16(kf, qf, zero, 0, 0, 0);
    }
    float m = st[0][0];
    #pragma unroll
    for (int T = 0; T < 16; ++T)
      #pragma unroll
      for (int r = 0; r < 4; ++r) m = fmaxf(m, st[T][r]);
    m = fmaxf(m, __shfl_xor(m, 16, 64));
    m = fmaxf(m, __shfl_xor(m, 32, 64));
    float l = 0.f;
    #pragma unroll
    for (int T = 0; T < 16; ++T)
      #pragma unroll
      for (int r = 0; r < 4; ++r) {
        float p = __expf((st[T][r] - m) * scale);
        st[T][r] = p;
        l += p;
      }
    l += __shfl_xor(l, 16, 64);
    l += __shfl_xor(l, 32, 64);
    float inv = 1.0f / l;
    f32x4 oa0 = zero, oa1 = zero;
    #pragma unroll
    for (int g = 0; g < 8; ++g) {
      // pf = [st2g[0..3], st2g+1[0..3]] (same element order as verified pk[])
      uint4 pw = make_uint4(cvt_pk_bf16(st[2 * g][0], st[2 * g][1]),
                            cvt_pk_bf16(st[2 * g][2], st[2 * g][3]),
                            cvt_pk_bf16(st[2 * g + 1][0], st[2 * g + 1][1]),
                            cvt_pk_bf16(st[2 * g + 1][2], st[2 * g + 1][3]));
      bf16x8 pf = *(bf16x8*)&pw;
      bf16x8 va = *(const bf16x8*)&vperm[(g * 4 + quad) * 264 + n16 * 8];
      bf16x8 vb = *(const bf16x8*)&vperm[(g * 4 + quad) * 264 + (16 + n16) * 8];
      oa0 = __builtin_amdgcn_mfma_f32_16x16x32_bf16(va, pf, oa0, 0, 0, 0);
      oa1 = __builtin_amdgcn_mfma_f32_16x16x32_bf16(vb, pf, oa1, 0, 0, 0);
    }
    bfu* ob = o + ((size_t)reg * 256 + mt * 16 + n16) * 128 + h * 32 + quad * 4;
    unsigned o0 = cvt_pk_bf16(oa0[0] * inv, oa0[1] * inv);
    unsigned o1 = cvt_pk_bf16(oa0[2] * inv, oa0[3] * inv);
    unsigned o2 = cvt_pk_bf16(oa1[0] * inv, oa1[1] * inv);
    unsigned o3 = cvt_pk_bf16(oa1[2] * inv, oa1[3] * inv);
    *(uint2*)&ob[0] = make_uint2(o0, o1);
    *(uint2*)&ob[16] = make_uint2(o2, o3);
  }
}

// K4: tok[c][t] (bf16) += o @ w_out + b_out via MFMA, LDS-free
__global__ __launch_bounds__(256) void k4_outproj(
    const bfu* __restrict__ o, const bfu* __restrict__ awout,
    const float* __restrict__ bout, bfu* __restrict__ tok) {
  int reg = blockIdx.x;
  int tt = blockIdx.y;
  int tid = threadIdx.x;
  int wave = tid >> 6, lane = tid & 63;
  int quad = lane >> 4, n16 = lane & 15;
  int t = tt * 64 + wave * 16 + n16;
  const bfu* ob = o + ((size_t)reg * 256 + t) * 128;
  f32x4 acc[8];
  #pragma unroll
  for (int mt = 0; mt < 8; ++mt) acc[mt] = (f32x4){0.f, 0.f, 0.f, 0.f};
  #pragma unroll
  for (int kt = 0; kt < 4; ++kt) {
    bf16x8 bfrag = *(const bf16x8*)&ob[kt * 32 + quad * 8];
    const bfu* arow = awout + ((size_t)(kt * 4 + quad) * 128 + n16) * 8;
    #pragma unroll
    for (int mt = 0; mt < 8; ++mt) {
      bf16x8 afrag = *(const bf16x8*)&arow[mt * 128];
      acc[mt] = __builtin_amdgcn_mfma_f32_16x16x32_bf16(afrag, bfrag, acc[mt], 0, 0, 0);
    }
  }
  bfu* tokr = tok + (size_t)reg * DIMC * TT + t;
  #pragma unroll
  for (int mt = 0; mt < 8; ++mt) {
    #pragma unroll
    for (int rp = 0; rp < 2; ++rp) {
      int c = mt * 16 + quad * 4 + rp * 2;
      float v0 = bf2f(tokr[c * TT]) + acc[mt][rp * 2] + bout[c];
      float v1 = bf2f(tokr[(c + 1) * TT]) + acc[mt][rp * 2 + 1] + bout[c + 1];
      unsigned pk = cvt_pk_bf16(v0, v1);
      tokr[c * TT] = (bfu)pk;
      tokr[(c + 1) * TT] = (bfu)(pk >> 16);
    }
  }
}

// K5: overlap merge (bf16 tok) -> xf fp32 + xln bf16 blocked [b][cg][p][8c]
__global__ __launch_bounds__(512) void k5_merge(
    const bfu* __restrict__ tok, const float* __restrict__ ln2g,
    const float* __restrict__ ln2b, float* __restrict__ xf,
    bfu* __restrict__ xln) {
  int hh = blockIdx.x, b = blockIdx.y;
  int tid = threadIdx.x;
  int w = tid & 127, q = tid >> 7;
  int ilo = (hh >= 2) ? (hh - 2) / 14 : 0;
  int ihi = hh / 14;
  if (ihi > 8) ihi = 8;
  int jlo = (w >= 2) ? (w - 2) / 14 : 0;
  int jhi = w / 14;
  if (jhi > 8) jhi = 8;
  float rcnt = 1.0f / (float)((ihi - ilo + 1) * (jhi - jlo + 1));
  size_t offs[4];
  int nij = 0;
  for (int i = ilo; i <= ihi; ++i)
    for (int j = jlo; j <= jhi; ++j) {
      int reg = b * NREGB + i * NR + j;
      int r = hh - i * STEP, s = w - j * STEP;
      offs[nij++] = (size_t)reg * DIMC * TT + r * 16 + s;
    }
  float* xp = xf + ((size_t)b * DIMC << 14) + hh * WW_ + w;
  float mm[32];
  float sum = 0.f, sq = 0.f;
  int c0 = q * 32;
  for (int cc = 0; cc < 32; ++cc) {
    int c = c0 + cc;
    float s = 0.f;
    for (int k = 0; k < nij; ++k) s += bf2f(tok[offs[k] + c * TT]);
    float m = s * rcnt;
    xp[(size_t)c << 14] = m;
    mm[cc] = m;
    sum += m;
    sq = fmaf(m, m, sq);
  }
  __shared__ float rs[512];
  __shared__ float rq[512];
  __shared__ float muS[128];
  __shared__ float rsdS[128];
  rs[tid] = sum;
  rq[tid] = sq;
  __syncthreads();
  if (tid < 128) {
    float s4 = rs[tid] + rs[tid + 128] + rs[tid + 256] + rs[tid + 384];
    float q4 = rq[tid] + rq[tid + 128] + rq[tid + 256] + rq[tid + 384];
    float mu = s4 * (1.0f / DIMC);
    float var = q4 * (1.0f / DIMC) - mu * mu;
    muS[tid] = mu;
    rsdS[tid] = rsqrtf(var + 1e-5f);
  }
  __syncthreads();
  float mu = muS[w], rstd = rsdS[w];
  int p = hh * WW_ + w;
  #pragma unroll
  for (int gl = 0; gl < 4; ++gl) {
    int gidx = q * 4 + gl;
    float y[8];
    #pragma unroll
    for (int j = 0; j < 8; ++j) {
      int c = gidx * 8 + j;
      y[j] = (mm[gl * 8 + j] - mu) * rstd * ln2g[c] + ln2b[c];
    }
    uint4 pk = make_uint4(cvt_pk_bf16(y[0], y[1]), cvt_pk_bf16(y[2], y[3]),
                          cvt_pk_bf16(y[4], y[5]), cvt_pk_bf16(y[6], y[7]));
    *(uint4*)&xln[(((size_t)(b * 16 + gidx) << 14) + p) * 8] = pk;
  }
}

// K6: ym[b][f][p] = xln @ w_p0 + b_p0 via MFMA
__global__ __launch_bounds__(256) void k6_p0(
    const bfu* __restrict__ xln, const bfu* __restrict__ ap0,
    const float* __restrict__ bp0, bfu* __restrict__ ym) {
  int b = blockIdx.y;
  int ptile = blockIdx.x * 64;
  int tid = threadIdx.x;
  int wv = tid >> 6, lane = tid & 63;
  int quad = lane >> 4, n16 = lane & 15;
  int p = ptile + wv * 16 + n16;
  f32x4 acc[16];
  #pragma unroll
  for (int mt = 0; mt < 16; ++mt) acc[mt] = (f32x4){0.f, 0.f, 0.f, 0.f};
  #pragma unroll
  for (int ph = 0; ph < 4; ++ph) {
    int gg = ph * 4 + quad;
    bf16x8 bfrag = *(const bf16x8*)&xln[(((size_t)(b * 16 + gg) << 14) + p) * 8];
    const bfu* arow = ap0 + ((size_t)gg * 256 + n16) * 8;
    #pragma unroll
    for (int mt = 0; mt < 16; ++mt) {
      bf16x8 afrag = *(const bf16x8*)&arow[mt * 128];
      acc[mt] = __builtin_amdgcn_mfma_f32_16x16x32_bf16(afrag, bfrag, acc[mt], 0, 0, 0);
    }
  }
  #pragma unroll
  for (int mt = 0; mt < 16; ++mt) {
    #pragma unroll
    for (int rp = 0; rp < 2; ++rp) {
      int f = mt * 16 + quad * 4 + rp * 2;
      float v0 = acc[mt][rp * 2] + bp0[f];
      float v1 = acc[mt][rp * 2 + 1] + bp0[f + 1];
      unsigned pk = cvt_pk_bf16(v0, v1);
      ym[((size_t)(b * HID + f) << 14) + p] = (bfu)pk;
      ym[((size_t)(b * HID + f + 1) << 14) + p] = (bfu)(pk >> 16);
    }
  }
}

// K7: 5x5 depthwise conv, whole plane in LDS, fused BN partials
__global__ __launch_bounds__(256) void k7_conv(
    const bfu* __restrict__ ym, const float* __restrict__ dwk,
    bfu* __restrict__ ym2, float* __restrict__ bnacc) {
  int bf = blockIdx.x;
  int f = bf & (HID - 1);
  __shared__ bfu sp[128 * 134];
  const bfu* in = ym + ((size_t)bf << 14);
  int tid = threadIdx.x;
  for (int idx = tid; idx < 2048; idx += 256) {
    int r = idx >> 4, c8 = (idx & 15) << 3;
    ushort4 a = *(const ushort4*)&in[(r << 7) + c8];
    ushort4 b = *(const ushort4*)&in[(r << 7) + c8 + 4];
    bfu* d = &sp[r * 134 + c8];
    d[0] = a.x; d[1] = a.y; d[2] = a.z; d[3] = a.w;
    d[4] = b.x; d[5] = b.y; d[6] = b.z; d[7] = b.w;
  }
  float wk[25];
  #pragma unroll
  for (int i = 0; i < 25; ++i) wk[i] = dwk[f * 25 + i];
  __syncthreads();
  int row = tid >> 1, half = (tid & 1) << 6;
  float acc[64];
  #pragma unroll
  for (int i = 0; i < 64; ++i) acc[i] = 0.f;
  #pragma unroll
  for (int ky = 0; ky < 5; ++ky) {
    int y = row + ky - 2;
    if (y < 0 || y >= 128) continue;
    const bfu* rp = &sp[y * 134];
    float win[68];
    #pragma unroll
    for (int c = 0; c < 68; ++c) {
      int cc = half + c - 2;
      win[c] = (cc >= 0 && cc < 128) ? bf2f(rp[cc]) : 0.f;
    }
    #pragma unroll
    for (int kx = 0; kx < 5; ++kx) {
      float wv = wk[ky * 5 + kx];
      #pragma unroll
      for (int i = 0; i < 64; ++i) acc[i] = fmaf(win[i + kx], wv, acc[i]);
    }
  }
  float s = 0.f, sq = 0.f;
  #pragma unroll
  for (int i = 0; i < 64; ++i) {
    s += acc[i];
    sq = fmaf(acc[i], acc[i], sq);
  }
  bfu* op = ym2 + ((size_t)bf << 14) + (row << 7) + half;
  #pragma unroll
  for (int g8 = 0; g8 < 8; ++g8) {
    uint4 pk = make_uint4(cvt_pk_bf16(acc[g8 * 8 + 0], acc[g8 * 8 + 1]),
                          cvt_pk_bf16(acc[g8 * 8 + 2], acc[g8 * 8 + 3]),
                          cvt_pk_bf16(acc[g8 * 8 + 4], acc[g8 * 8 + 5]),
                          cvt_pk_bf16(acc[g8 * 8 + 6], acc[g8 * 8 + 7]));
    *(uint4*)&op[g8 * 8] = pk;
  }
  __syncthreads();
  float* red = (float*)sp;
  red[tid] = s;
  red[256 + tid] = sq;
  __syncthreads();
  for (int o = 128; o > 0; o >>= 1) {
    if (tid < o) {
      red[tid] += red[tid + o];
      red[256 + tid] += red[256 + tid + o];
    }
    __syncthreads();
  }
  if (tid == 0) {
    atomicAdd(&bnacc[f], red[0]);
    atomicAdd(&bnacc[HID + f], red[256]);
  }
}

// K10: out = gelu(gelu(bn(ym2))) @ w_p2 + b_p2 + xf via MFMA.
// BN finalize folded into a block prologue (R11-verified).
__global__ __launch_bounds__(256) void k10_p2(
    const bfu* __restrict__ ym2, const float* __restrict__ bnacc,
    const float* __restrict__ bng, const float* __restrict__ bnb,
    const bfu* __restrict__ ap2, const float* __restrict__ bp2,
    const float* __restrict__ xf, float* __restrict__ outp) {
  int b = blockIdx.y;
  int ptile = blockIdx.x * 64;
  int tid = threadIdx.x;
  __shared__ float sA[HID];
  __shared__ float sB[HID];
  {
    float mu = bnacc[tid] * (1.0f / 65536.f);
    float var = bnacc[HID + tid] * (1.0f / 65536.f) - mu * mu;
    float sa = rsqrtf(var + 1e-5f) * bng[tid];
    sA[tid] = sa;
    sB[tid] = bnb[tid] - mu * sa;
  }
  __syncthreads();
  int wv = tid >> 6, lane = tid & 63;
  int quad = lane >> 4, n16 = lane & 15;
  int p = ptile + wv * 16 + n16;
  f32x4 acc[8];
  #pragma unroll
  for (int mt = 0; mt < 8; ++mt) acc[mt] = (f32x4){0.f, 0.f, 0.f, 0.f};
  #pragma unroll
  for (int ph = 0; ph < 8; ++ph) {
    int gg = ph * 4 + quad;
    const bfu* ymp = ym2 + (((size_t)(b * HID + gg * 8)) << 14) + p;
    float vals[8];
    #pragma unroll
    for (int j = 0; j < 8; ++j) vals[j] = bf2f(ymp[(size_t)j << 14]);
    float gv[8];
    #pragma unroll
    for (int j = 0; j < 8; ++j) {
      float v = fmaf(vals[j], sA[gg * 8 + j], sB[gg * 8 + j]);
      gv[j] = gelu_exact(gelu_exact(v));
    }
    uint4 pk = make_uint4(cvt_pk_bf16(gv[0], gv[1]), cvt_pk_bf16(gv[2], gv[3]),
                          cvt_pk_bf16(gv[4], gv[5]), cvt_pk_bf16(gv[6], gv[7]));
    bf16x8 bfrag = *(bf16x8*)&pk;
    const bfu* arow = ap2 + ((size_t)gg * 128 + n16) * 8;
    #pragma unroll
    for (int mt = 0; mt < 8; ++mt) {
      bf16x8 afrag = *(const bf16x8*)&arow[mt * 128];
      acc[mt] = __builtin_amdgcn_mfma_f32_16x16x32_bf16(afrag, bfrag, acc[mt], 0, 0, 0);
    }
  }
  #pragma unroll
  for (int mt = 0; mt < 8; ++mt) {
    #pragma unroll
    for (int r = 0; r < 4; ++r) {
      int c = mt * 16 + quad * 4 + r;
      size_t off = ((size_t)(b * DIMC + c) << 14) + p;
      outp[off] = acc[mt][r] + bp2[c] + xf[off];
    }
  }
}

extern "C" void kernel_launch(void* const* d_in, const int* in_sizes, int n_in,
                              void* d_out, int out_size, void* d_ws,
                              size_t ws_size, hipStream_t stream) {
  const float* x = (const float*)d_in[0];
  const float* ln1_g = (const float*)d_in[1];
  const float* ln1_b = (const float*)d_in[2];
  const float* w_qkv = (const float*)d_in[3];
  const float* w_out = (const float*)d_in[4];
  const float* b_out = (const float*)d_in[5];
  const float* ln2_g = (const float*)d_in[6];
  const float* ln2_b = (const float*)d_in[7];
  const float* w_p0 = (const float*)d_in[8];
  const float* b_p0 = (const float*)d_in[9];
  const float* dw_k = (const float*)d_in[10];
  const float* bn_g = (const float*)d_in[11];
  const float* bn_b = (const float*)d_in[12];
  const float* w_p2 = (const float*)d_in[13];
  const float* b_p2 = (const float*)d_in[14];
  float* outp = (float*)d_out;

  char* ws = (char*)d_ws;
  size_t off = 0;
  auto alloc = [&](size_t bytes) {
    void* p = ws + off;
    off += (bytes + 1023) & ~(size_t)1023;
    return p;
  };
  bfu* tok = (bfu*)alloc((size_t)NREG * DIMC * TT * 2);
  float* xf = (float*)alloc((size_t)BB * DIMC * HW * 4);
  bfu* xln = (bfu*)alloc((size_t)BB * DIMC * HW * 2);
  bfu* ym = (bfu*)alloc((size_t)BB * HID * HW * 2);
  bfu* ym2 = (bfu*)alloc((size_t)BB * HID * HW * 2);
  float* bnacc = (float*)alloc(2 * HID * 4);
  bfu* wqkvT = (bfu*)alloc(16 * 3072 * 2);
  bfu* ap0 = (bfu*)alloc(16 * 256 * 8 * 2);
  bfu* ap2 = (bfu*)alloc(32 * 128 * 8 * 2);
  bfu* awout = (bfu*)alloc(16 * 128 * 8 * 2);
  // overlays (lifetimes disjoint)
  bfu* o = ym;     // used k23->k4; ym written first in k6
  bfu* aln = ym2;  // used k1->k23; ym2 written first in k7

  // k1 grid: NREG gather blocks + 65 weight-prep blocks (former kprep)
  k1_gather<<<NREG + 65, 256, 0, stream>>>(x, ln1_g, ln1_b, tok, aln, w_qkv,
                                           w_p0, w_p2, w_out, wqkvT, ap0, ap2,
                                           awout, bnacc);
  k23_fused<<<dim3(NREG, NHEADS), 256, 0, stream>>>(aln, wqkvT, o);
  k4_outproj<<<dim3(NREG, 4), 256, 0, stream>>>(o, awout, b_out, tok);
  k5_merge<<<dim3(HH_, BB), 512, 0, stream>>>(tok, ln2_g, ln2_b, xf, xln);
  k6_p0<<<dim3(256, BB), 256, 0, stream>>>(xln, ap0, b_p0, ym);
  k7_conv<<<BB * HID, 256, 0, stream>>>(ym, dw_k, ym2, bnacc);
  k10_p2<<<dim3(256, BB), 256, 0, stream>>>(ym2, bnacc, bn_g, bn_b, ap2, b_p2,
                                            xf, outp);
}

// Round 17
// 326.081 us; speedup vs baseline: 1.2086x; 1.0779x over previous
//
#include <hip/hip_runtime.h>

#define DIMC 128
#define NHEADS 4
#define HD 32
#define HID 256
#define BB 4
#define HH_ 128
#define WW_ 128
#define HW 16384
#define RS 16
#define STEP 14
#define NR 9
#define NREGB 81
#define NREG 324
#define TT 256

typedef unsigned short bfu;  // bf16 bits
typedef __attribute__((ext_vector_type(8))) short bf16x8;
typedef __attribute__((ext_vector_type(4))) float f32x4;

__device__ __forceinline__ float bf2f(bfu u) {
  return __uint_as_float(((unsigned int)u) << 16);
}
// HW packed f32->bf16 (RNE): dst.lo16 = bf16(lo), dst.hi16 = bf16(hi).
// Semantics hardware-verified R11/R12.
__device__ __forceinline__ unsigned cvt_pk_bf16(float lo, float hi) {
  unsigned r;
  asm("v_cvt_pk_bf16_f32 %0, %1, %2" : "=v"(r) : "v"(lo), "v"(hi));
  return r;
}
// tanh-form gelu: x * sigmoid(1.59577x + 0.07135x^3).
// Max |err| vs exact-erf gelu ~3e-4 (threshold headroom 0.10875 vs 0.031).
// Branch-free: ~8 VALU ops vs libm erff's ~30-40.
__device__ __forceinline__ float gelu_fast(float x) {
  float x2 = x * x;
  float z = x * fmaf(x2, 0.07135481627f, 1.5957691216f);
  float e = __expf(-z);
  return __fdividef(x, 1.0f + e);
}

// K1: gather -> tok bf16 [reg][c][t]; aln bf16 blocked [reg][g=c/8][t][8c]
// Blocks >= NREG run the weight-prep tail:
//  pb 0..23 wqkvT; pb 24 zero bnacc; pb 25..40 ap0; pb 41..56 ap2;
//  pb 57..64 awout
__global__ __launch_bounds__(256) void k1_gather(
    const float* __restrict__ x, const float* __restrict__ g,
    const float* __restrict__ bia, bfu* __restrict__ tok,
    bfu* __restrict__ aln, const float* __restrict__ wqkv,
    const float* __restrict__ wp0, const float* __restrict__ wp2,
    const float* __restrict__ wout, bfu* __restrict__ wqkvT,
    bfu* __restrict__ ap0, bfu* __restrict__ ap2, bfu* __restrict__ awout,
    float* __restrict__ bnacc) {
  int bid = blockIdx.x;
  int tid = threadIdx.x;
  if (bid >= NREG) {
    int pb = bid - NREG;
    if (pb < 24) {
      int task = pb * 256 + tid;  // kg*384 + n
      int kg = task / 384, n = task % 384;
      float v[8];
      #pragma unroll
      for (int j = 0; j < 8; ++j) v[j] = wqkv[(kg * 8 + j) * 384 + n];
      uint4 pk = make_uint4(cvt_pk_bf16(v[0], v[1]), cvt_pk_bf16(v[2], v[3]),
                            cvt_pk_bf16(v[4], v[5]), cvt_pk_bf16(v[6], v[7]));
      *(uint4*)&wqkvT[(size_t)kg * 3072 + n * 8] = pk;
    } else if (pb == 24) {
      bnacc[tid] = 0.f;
      bnacc[256 + tid] = 0.f;
    } else if (pb < 41) {
      int task = (pb - 25) * 256 + tid;  // kg*256 + f
      int kg = task >> 8, f = task & 255;
      float v[8];
      #pragma unroll
      for (int j = 0; j < 8; ++j) v[j] = wp0[(kg * 8 + j) * 256 + f];
      uint4 pk = make_uint4(cvt_pk_bf16(v[0], v[1]), cvt_pk_bf16(v[2], v[3]),
                            cvt_pk_bf16(v[4], v[5]), cvt_pk_bf16(v[6], v[7]));
      *(uint4*)&ap0[((size_t)kg * 256 + f) * 8] = pk;
    } else if (pb < 57) {
      int task = (pb - 41) * 256 + tid;  // kg*128 + c
      int kg = task >> 7, c = task & 127;
      float v[8];
      #pragma unroll
      for (int j = 0; j < 8; ++j) v[j] = wp2[(kg * 8 + j) * 128 + c];
      uint4 pk = make_uint4(cvt_pk_bf16(v[0], v[1]), cvt_pk_bf16(v[2], v[3]),
                            cvt_pk_bf16(v[4], v[5]), cvt_pk_bf16(v[6], v[7]));
      *(uint4*)&ap2[((size_t)kg * 128 + c) * 8] = pk;
    } else {
      int task = (pb - 57) * 256 + tid;  // kg*128 + c
      int kg = task >> 7, c = task & 127;
      float v[8];
      #pragma unroll
      for (int j = 0; j < 8; ++j) v[j] = wout[(kg * 8 + j) * 128 + c];
      uint4 pk = make_uint4(cvt_pk_bf16(v[0], v[1]), cvt_pk_bf16(v[2], v[3]),
                            cvt_pk_bf16(v[4], v[5]), cvt_pk_bf16(v[6], v[7]));
      *(uint4*)&awout[((size_t)kg * 128 + c) * 8] = pk;
    }
    return;
  }
  int reg = bid;
  int b = reg / NREGB, ij = reg % NREGB;
  int i = ij / NR, j = ij % NR;
  int t = tid;
  int r = t >> 4, s = t & 15;
  int hh = i * STEP + r, ww = j * STEP + s;
  const float* xp = x + (size_t)b * DIMC * HW + (size_t)hh * WW_ + ww;
  bfu* tp = tok + (size_t)reg * DIMC * TT + t;
  float sum = 0.f, sq = 0.f;
  #pragma unroll 4
  for (int c = 0; c < DIMC; c += 2) {
    float v0 = xp[(size_t)c * HW];
    float v1 = xp[(size_t)(c + 1) * HW];
    unsigned pk = cvt_pk_bf16(v0, v1);
    tp[c * TT] = (bfu)pk;
    tp[(c + 1) * TT] = (bfu)(pk >> 16);
    sum += v0 + v1;
    sq = fmaf(v0, v0, sq);
    sq = fmaf(v1, v1, sq);
  }
  float mu = sum * (1.0f / DIMC);
  float var = sq * (1.0f / DIMC) - mu * mu;
  float rstd = rsqrtf(var + 1e-5f);
  bfu* ap = aln + (size_t)reg * 32768 + t * 8;
  #pragma unroll
  for (int gidx = 0; gidx < 16; ++gidx) {
    float y[8];
    #pragma unroll
    for (int jj = 0; jj < 8; ++jj) {
      int c = gidx * 8 + jj;
      float vv = xp[(size_t)c * HW];  // L2-hot re-read
      y[jj] = (vv - mu) * rstd * g[c] + bia[c];
    }
    uint4 pk = make_uint4(cvt_pk_bf16(y[0], y[1]), cvt_pk_bf16(y[2], y[3]),
                          cvt_pk_bf16(y[4], y[5]), cvt_pk_bf16(y[6], y[7]));
    *(uint4*)&ap[(size_t)gidx * 2048] = pk;
  }
}

// K23: fused per-(region,head) QKV projection + attention.
// R12-verified structure; all pack sites use cvt_pk.
__global__ __launch_bounds__(256) void k23_fused(
    const bfu* __restrict__ aln, const bfu* __restrict__ wqkvT,
    bfu* __restrict__ o) {
  int reg = blockIdx.x;
  int h = blockIdx.y;
  __shared__ __align__(16) bfu sQ[256 * 40];        // [tok][d32 +8pad] 20.5KB
  __shared__ __align__(16) bfu sK[256 * 40];        // 20.5KB
  __shared__ __align__(16) bfu vperm[8 * 4 * 264];  // 16.9KB
  int tid = threadIdx.x;
  int wave = tid >> 6, lane = tid & 63;
  int quad = lane >> 4, n16 = lane & 15;

  // ---- QKV GEMM for this head: [256 tok x 96 cols] = aln @ W[:, cols(h)]
  const bfu* ab = aln + (size_t)reg * 32768 + (wave * 64 + n16) * 8;
  int colb[6];
  colb[0] = h * 32;        // q lo
  colb[1] = h * 32 + 16;   // q hi
  colb[2] = 128 + h * 32;  // k lo
  colb[3] = 144 + h * 32;  // k hi
  colb[4] = 256 + h * 32;  // v lo
  colb[5] = 272 + h * 32;  // v hi
  f32x4 acc[4][6];
  #pragma unroll
  for (int m = 0; m < 4; ++m)
    #pragma unroll
    for (int nt = 0; nt < 6; ++nt) acc[m][nt] = (f32x4){0.f, 0.f, 0.f, 0.f};
  #pragma unroll
  for (int ph = 0; ph < 4; ++ph) {
    int gg = ph * 4 + quad;
    bf16x8 af[4];
    #pragma unroll
    for (int m = 0; m < 4; ++m)
      af[m] = *(const bf16x8*)&ab[(size_t)gg * 2048 + m * 128];
    const bfu* bgg = wqkvT + (size_t)gg * 3072;
    bf16x8 bfr[6];
    #pragma unroll
    for (int nt = 0; nt < 6; ++nt)
      bfr[nt] = *(const bf16x8*)&bgg[(colb[nt] + n16) * 8];
    #pragma unroll
    for (int m = 0; m < 4; ++m)
      #pragma unroll
      for (int nt = 0; nt < 6; ++nt)
        acc[m][nt] =
            __builtin_amdgcn_mfma_f32_16x16x32_bf16(af[m], bfr[nt], acc[m][nt], 0, 0, 0);
  }
  // ---- scatter acc -> LDS (C/D map: row = quad*4+r, col = n16)
  // token t = wave*64 + m*16 + quad*4 + r; addressing identical to R11/R12.
  #pragma unroll
  for (int m = 0; m < 4; ++m) {
    int g = wave * 2 + (m >> 1);
    int jt = (m & 1) * 4;
    int T0 = wave * 64 + m * 16 + quad * 4;
    unsigned q00 = cvt_pk_bf16(acc[m][0][0], acc[m][0][1]);
    unsigned q01 = cvt_pk_bf16(acc[m][0][2], acc[m][0][3]);
    unsigned q10 = cvt_pk_bf16(acc[m][1][0], acc[m][1][1]);
    unsigned q11 = cvt_pk_bf16(acc[m][1][2], acc[m][1][3]);
    unsigned k00 = cvt_pk_bf16(acc[m][2][0], acc[m][2][1]);
    unsigned k01 = cvt_pk_bf16(acc[m][2][2], acc[m][2][3]);
    unsigned k10 = cvt_pk_bf16(acc[m][3][0], acc[m][3][1]);
    unsigned k11 = cvt_pk_bf16(acc[m][3][2], acc[m][3][3]);
    sQ[(T0 + 0) * 40 + n16] = (bfu)q00;
    sQ[(T0 + 1) * 40 + n16] = (bfu)(q00 >> 16);
    sQ[(T0 + 2) * 40 + n16] = (bfu)q01;
    sQ[(T0 + 3) * 40 + n16] = (bfu)(q01 >> 16);
    sQ[(T0 + 0) * 40 + 16 + n16] = (bfu)q10;
    sQ[(T0 + 1) * 40 + 16 + n16] = (bfu)(q10 >> 16);
    sQ[(T0 + 2) * 40 + 16 + n16] = (bfu)q11;
    sQ[(T0 + 3) * 40 + 16 + n16] = (bfu)(q11 >> 16);
    sK[(T0 + 0) * 40 + n16] = (bfu)k00;
    sK[(T0 + 1) * 40 + n16] = (bfu)(k00 >> 16);
    sK[(T0 + 2) * 40 + n16] = (bfu)k01;
    sK[(T0 + 3) * 40 + n16] = (bfu)(k01 >> 16);
    sK[(T0 + 0) * 40 + 16 + n16] = (bfu)k10;
    sK[(T0 + 1) * 40 + 16 + n16] = (bfu)(k10 >> 16);
    sK[(T0 + 2) * 40 + 16 + n16] = (bfu)k11;
    sK[(T0 + 3) * 40 + 16 + n16] = (bfu)(k11 >> 16);
    unsigned v0 = cvt_pk_bf16(acc[m][4][0], acc[m][4][1]);
    unsigned v1 = cvt_pk_bf16(acc[m][4][2], acc[m][4][3]);
    unsigned v2 = cvt_pk_bf16(acc[m][5][0], acc[m][5][1]);
    unsigned v3 = cvt_pk_bf16(acc[m][5][2], acc[m][5][3]);
    int vbase = (g * 4 + quad) * 264 + jt;
    *(uint2*)&vperm[vbase + n16 * 8] = make_uint2(v0, v1);
    *(uint2*)&vperm[vbase + (16 + n16) * 8] = make_uint2(v2, v3);
  }
  __syncthreads();

  // ---- attention (R12-verified body) ----
  const f32x4 zero = {0.f, 0.f, 0.f, 0.f};
  const float scale = 0.17677669529663687f;  // 1/sqrt(32)
  for (int mi = 0; mi < 4; ++mi) {
    int mt = wave * 4 + mi;
    bf16x8 qf = *(const bf16x8*)&sQ[(mt * 16 + n16) * 40 + quad * 8];
    f32x4 st[16];
    #pragma unroll
    for (int T = 0; T < 16; ++T) {
      bf16x8 kf = *(const bf16x8*)&sK[(T * 16 + n16) * 40 + quad * 8];
      st[T] = __builtin_amdgcn_mfma_f32_16x16x32_bf16(kf, qf, zero, 0, 0, 0);
    }
    float m = st[0][0];
    #pragma unroll
    for (int T = 0; T < 16; ++T)
      #pragma unroll
      for (int r = 0; r < 4; ++r) m = fmaxf(m, st[T][r]);
    m = fmaxf(m, __shfl_xor(m, 16, 64));
    m = fmaxf(m, __shfl_xor(m, 32, 64));
    float l = 0.f;
    #pragma unroll
    for (int T = 0; T < 16; ++T)
      #pragma unroll
      for (int r = 0; r < 4; ++r) {
        float p = __expf((st[T][r] - m) * scale);
        st[T][r] = p;
        l += p;
      }
    l += __shfl_xor(l, 16, 64);
    l += __shfl_xor(l, 32, 64);
    float inv = 1.0f / l;
    f32x4 oa0 = zero, oa1 = zero;
    #pragma unroll
    for (int g = 0; g < 8; ++g) {
      uint4 pw = make_uint4(cvt_pk_bf16(st[2 * g][0], st[2 * g][1]),
                            cvt_pk_bf16(st[2 * g][2], st[2 * g][3]),
                            cvt_pk_bf16(st[2 * g + 1][0], st[2 * g + 1][1]),
                            cvt_pk_bf16(st[2 * g + 1][2], st[2 * g + 1][3]));
      bf16x8 pf = *(bf16x8*)&pw;
      bf16x8 va = *(const bf16x8*)&vperm[(g * 4 + quad) * 264 + n16 * 8];
      bf16x8 vb = *(const bf16x8*)&vperm[(g * 4 + quad) * 264 + (16 + n16) * 8];
      oa0 = __builtin_amdgcn_mfma_f32_16x16x32_bf16(va, pf, oa0, 0, 0, 0);
      oa1 = __builtin_amdgcn_mfma_f32_16x16x32_bf16(vb, pf, oa1, 0, 0, 0);
    }
    bfu* ob = o + ((size_t)reg * 256 + mt * 16 + n16) * 128 + h * 32 + quad * 4;
    unsigned o0 = cvt_pk_bf16(oa0[0] * inv, oa0[1] * inv);
    unsigned o1 = cvt_pk_bf16(oa0[2] * inv, oa0[3] * inv);
    unsigned o2 = cvt_pk_bf16(oa1[0] * inv, oa1[1] * inv);
    unsigned o3 = cvt_pk_bf16(oa1[2] * inv, oa1[3] * inv);
    *(uint2*)&ob[0] = make_uint2(o0, o1);
    *(uint2*)&ob[16] = make_uint2(o2, o3);
  }
}

// K4: tok[c][t] (bf16) += o @ w_out + b_out via MFMA, LDS-free
__global__ __launch_bounds__(256) void k4_outproj(
    const bfu* __restrict__ o, const bfu* __restrict__ awout,
    const float* __restrict__ bout, bfu* __restrict__ tok) {
  int reg = blockIdx.x;
  int tt = blockIdx.y;
  int tid = threadIdx.x;
  int wave = tid >> 6, lane = tid & 63;
  int quad = lane >> 4, n16 = lane & 15;
  int t = tt * 64 + wave * 16 + n16;
  const bfu* ob = o + ((size_t)reg * 256 + t) * 128;
  f32x4 acc[8];
  #pragma unroll
  for (int mt = 0; mt < 8; ++mt) acc[mt] = (f32x4){0.f, 0.f, 0.f, 0.f};
  #pragma unroll
  for (int kt = 0; kt < 4; ++kt) {
    bf16x8 bfrag = *(const bf16x8*)&ob[kt * 32 + quad * 8];
    const bfu* arow = awout + ((size_t)(kt * 4 + quad) * 128 + n16) * 8;
    #pragma unroll
    for (int mt = 0; mt < 8; ++mt) {
      bf16x8 afrag = *(const bf16x8*)&arow[mt * 128];
      acc[mt] = __builtin_amdgcn_mfma_f32_16x16x32_bf16(afrag, bfrag, acc[mt], 0, 0, 0);
    }
  }
  bfu* tokr = tok + (size_t)reg * DIMC * TT + t;
  #pragma unroll
  for (int mt = 0; mt < 8; ++mt) {
    #pragma unroll
    for (int rp = 0; rp < 2; ++rp) {
      int c = mt * 16 + quad * 4 + rp * 2;
      float v0 = bf2f(tokr[c * TT]) + acc[mt][rp * 2] + bout[c];
      float v1 = bf2f(tokr[(c + 1) * TT]) + acc[mt][rp * 2 + 1] + bout[c + 1];
      unsigned pk = cvt_pk_bf16(v0, v1);
      tokr[c * TT] = (bfu)pk;
      tokr[(c + 1) * TT] = (bfu)(pk >> 16);
    }
  }
}

// K5: overlap merge (bf16 tok) -> xf fp32 + xln bf16 blocked [b][cg][p][8c]
__global__ __launch_bounds__(512) void k5_merge(
    const bfu* __restrict__ tok, const float* __restrict__ ln2g,
    const float* __restrict__ ln2b, float* __restrict__ xf,
    bfu* __restrict__ xln) {
  int hh = blockIdx.x, b = blockIdx.y;
  int tid = threadIdx.x;
  int w = tid & 127, q = tid >> 7;
  int ilo = (hh >= 2) ? (hh - 2) / 14 : 0;
  int ihi = hh / 14;
  if (ihi > 8) ihi = 8;
  int jlo = (w >= 2) ? (w - 2) / 14 : 0;
  int jhi = w / 14;
  if (jhi > 8) jhi = 8;
  float rcnt = 1.0f / (float)((ihi - ilo + 1) * (jhi - jlo + 1));
  size_t offs[4];
  int nij = 0;
  for (int i = ilo; i <= ihi; ++i)
    for (int j = jlo; j <= jhi; ++j) {
      int reg = b * NREGB + i * NR + j;
      int r = hh - i * STEP, s = w - j * STEP;
      offs[nij++] = (size_t)reg * DIMC * TT + r * 16 + s;
    }
  float* xp = xf + ((size_t)b * DIMC << 14) + hh * WW_ + w;
  float mm[32];
  float sum = 0.f, sq = 0.f;
  int c0 = q * 32;
  for (int cc = 0; cc < 32; ++cc) {
    int c = c0 + cc;
    float s = 0.f;
    for (int k = 0; k < nij; ++k) s += bf2f(tok[offs[k] + c * TT]);
    float m = s * rcnt;
    xp[(size_t)c << 14] = m;
    mm[cc] = m;
    sum += m;
    sq = fmaf(m, m, sq);
  }
  __shared__ float rs[512];
  __shared__ float rq[512];
  __shared__ float muS[128];
  __shared__ float rsdS[128];
  rs[tid] = sum;
  rq[tid] = sq;
  __syncthreads();
  if (tid < 128) {
    float s4 = rs[tid] + rs[tid + 128] + rs[tid + 256] + rs[tid + 384];
    float q4 = rq[tid] + rq[tid + 128] + rq[tid + 256] + rq[tid + 384];
    float mu = s4 * (1.0f / DIMC);
    float var = q4 * (1.0f / DIMC) - mu * mu;
    muS[tid] = mu;
    rsdS[tid] = rsqrtf(var + 1e-5f);
  }
  __syncthreads();
  float mu = muS[w], rstd = rsdS[w];
  int p = hh * WW_ + w;
  #pragma unroll
  for (int gl = 0; gl < 4; ++gl) {
    int gidx = q * 4 + gl;
    float y[8];
    #pragma unroll
    for (int j = 0; j < 8; ++j) {
      int c = gidx * 8 + j;
      y[j] = (mm[gl * 8 + j] - mu) * rstd * ln2g[c] + ln2b[c];
    }
    uint4 pk = make_uint4(cvt_pk_bf16(y[0], y[1]), cvt_pk_bf16(y[2], y[3]),
                          cvt_pk_bf16(y[4], y[5]), cvt_pk_bf16(y[6], y[7]));
    *(uint4*)&xln[(((size_t)(b * 16 + gidx) << 14) + p) * 8] = pk;
  }
}

// K6: ym[b][f][p] = xln @ w_p0 + b_p0 via MFMA
__global__ __launch_bounds__(256) void k6_p0(
    const bfu* __restrict__ xln, const bfu* __restrict__ ap0,
    const float* __restrict__ bp0, bfu* __restrict__ ym) {
  int b = blockIdx.y;
  int ptile = blockIdx.x * 64;
  int tid = threadIdx.x;
  int wv = tid >> 6, lane = tid & 63;
  int quad = lane >> 4, n16 = lane & 15;
  int p = ptile + wv * 16 + n16;
  f32x4 acc[16];
  #pragma unroll
  for (int mt = 0; mt < 16; ++mt) acc[mt] = (f32x4){0.f, 0.f, 0.f, 0.f};
  #pragma unroll
  for (int ph = 0; ph < 4; ++ph) {
    int gg = ph * 4 + quad;
    bf16x8 bfrag = *(const bf16x8*)&xln[(((size_t)(b * 16 + gg) << 14) + p) * 8];
    const bfu* arow = ap0 + ((size_t)gg * 256 + n16) * 8;
    #pragma unroll
    for (int mt = 0; mt < 16; ++mt) {
      bf16x8 afrag = *(const bf16x8*)&arow[mt * 128];
      acc[mt] = __builtin_amdgcn_mfma_f32_16x16x32_bf16(afrag, bfrag, acc[mt], 0, 0, 0);
    }
  }
  #pragma unroll
  for (int mt = 0; mt < 16; ++mt) {
    #pragma unroll
    for (int rp = 0; rp < 2; ++rp) {
      int f = mt * 16 + quad * 4 + rp * 2;
      float v0 = acc[mt][rp * 2] + bp0[f];
      float v1 = acc[mt][rp * 2 + 1] + bp0[f + 1];
      unsigned pk = cvt_pk_bf16(v0, v1);
      ym[((size_t)(b * HID + f) << 14) + p] = (bfu)pk;
      ym[((size_t)(b * HID + f + 1) << 14) + p] = (bfu)(pk >> 16);
    }
  }
}

// K7: 5x5 depthwise conv, whole plane in LDS, fused BN partials
__global__ __launch_bounds__(256) void k7_conv(
    const bfu* __restrict__ ym, const float* __restrict__ dwk,
    bfu* __restrict__ ym2, float* __restrict__ bnacc) {
  int bf = blockIdx.x;
  int f = bf & (HID - 1);
  __shared__ bfu sp[128 * 134];
  const bfu* in = ym + ((size_t)bf << 14);
  int tid = threadIdx.x;
  for (int idx = tid; idx < 2048; idx += 256) {
    int r = idx >> 4, c8 = (idx & 15) << 3;
    ushort4 a = *(const ushort4*)&in[(r << 7) + c8];
    ushort4 b = *(const ushort4*)&in[(r << 7) + c8 + 4];
    bfu* d = &sp[r * 134 + c8];
    d[0] = a.x; d[1] = a.y; d[2] = a.z; d[3] = a.w;
    d[4] = b.x; d[5] = b.y; d[6] = b.z; d[7] = b.w;
  }
  float wk[25];
  #pragma unroll
  for (int i = 0; i < 25; ++i) wk[i] = dwk[f * 25 + i];
  __syncthreads();
  int row = tid >> 1, half = (tid & 1) << 6;
  float acc[64];
  #pragma unroll
  for (int i = 0; i < 64; ++i) acc[i] = 0.f;
  #pragma unroll
  for (int ky = 0; ky < 5; ++ky) {
    int y = row + ky - 2;
    if (y < 0 || y >= 128) continue;
    const bfu* rp = &sp[y * 134];
    float win[68];
    #pragma unroll
    for (int c = 0; c < 68; ++c) {
      int cc = half + c - 2;
      win[c] = (cc >= 0 && cc < 128) ? bf2f(rp[cc]) : 0.f;
    }
    #pragma unroll
    for (int kx = 0; kx < 5; ++kx) {
      float wv = wk[ky * 5 + kx];
      #pragma unroll
      for (int i = 0; i < 64; ++i) acc[i] = fmaf(win[i + kx], wv, acc[i]);
    }
  }
  float s = 0.f, sq = 0.f;
  #pragma unroll
  for (int i = 0; i < 64; ++i) {
    s += acc[i];
    sq = fmaf(acc[i], acc[i], sq);
  }
  bfu* op = ym2 + ((size_t)bf << 14) + (row << 7) + half;
  #pragma unroll
  for (int g8 = 0; g8 < 8; ++g8) {
    uint4 pk = make_uint4(cvt_pk_bf16(acc[g8 * 8 + 0], acc[g8 * 8 + 1]),
                          cvt_pk_bf16(acc[g8 * 8 + 2], acc[g8 * 8 + 3]),
                          cvt_pk_bf16(acc[g8 * 8 + 4], acc[g8 * 8 + 5]),
                          cvt_pk_bf16(acc[g8 * 8 + 6], acc[g8 * 8 + 7]));
    *(uint4*)&op[g8 * 8] = pk;
  }
  __syncthreads();
  float* red = (float*)sp;
  red[tid] = s;
  red[256 + tid] = sq;
  __syncthreads();
  for (int o = 128; o > 0; o >>= 1) {
    if (tid < o) {
      red[tid] += red[tid + o];
      red[256 + tid] += red[256 + tid + o];
    }
    __syncthreads();
  }
  if (tid == 0) {
    atomicAdd(&bnacc[f], red[0]);
    atomicAdd(&bnacc[HID + f], red[256]);
  }
}

// K10: out = gelu(gelu(bn(ym2))) @ w_p2 + b_p2 + xf via MFMA.
// BN finalize folded into a block prologue (R11-verified).
// R13 delta: double-gelu via tanh-form gelu_fast (erff -> exp-based sigmoid).
__global__ __launch_bounds__(256) void k10_p2(
    const bfu* __restrict__ ym2, const float* __restrict__ bnacc,
    const float* __restrict__ bng, const float* __restrict__ bnb,
    const bfu* __restrict__ ap2, const float* __restrict__ bp2,
    const float* __restrict__ xf, float* __restrict__ outp) {
  int b = blockIdx.y;
  int ptile = blockIdx.x * 64;
  int tid = threadIdx.x;
  __shared__ float sA[HID];
  __shared__ float sB[HID];
  {
    float mu = bnacc[tid] * (1.0f / 65536.f);
    float var = bnacc[HID + tid] * (1.0f / 65536.f) - mu * mu;
    float sa = rsqrtf(var + 1e-5f) * bng[tid];
    sA[tid] = sa;
    sB[tid] = bnb[tid] - mu * sa;
  }
  __syncthreads();
  int wv = tid >> 6, lane = tid & 63;
  int quad = lane >> 4, n16 = lane & 15;
  int p = ptile + wv * 16 + n16;
  f32x4 acc[8];
  #pragma unroll
  for (int mt = 0; mt < 8; ++mt) acc[mt] = (f32x4){0.f, 0.f, 0.f, 0.f};
  #pragma unroll
  for (int ph = 0; ph < 8; ++ph) {
    int gg = ph * 4 + quad;
    const bfu* ymp = ym2 + (((size_t)(b * HID + gg * 8)) << 14) + p;
    float vals[8];
    #pragma unroll
    for (int j = 0; j < 8; ++j) vals[j] = bf2f(ymp[(size_t)j << 14]);
    float gv[8];
    #pragma unroll
    for (int j = 0; j < 8; ++j) {
      float v = fmaf(vals[j], sA[gg * 8 + j], sB[gg * 8 + j]);
      gv[j] = gelu_fast(gelu_fast(v));
    }
    uint4 pk = make_uint4(cvt_pk_bf16(gv[0], gv[1]), cvt_pk_bf16(gv[2], gv[3]),
                          cvt_pk_bf16(gv[4], gv[5]), cvt_pk_bf16(gv[6], gv[7]));
    bf16x8 bfrag = *(bf16x8*)&pk;
    const bfu* arow = ap2 + ((size_t)gg * 128 + n16) * 8;
    #pragma unroll
    for (int mt = 0; mt < 8; ++mt) {
      bf16x8 afrag = *(const bf16x8*)&arow[mt * 128];
      acc[mt] = __builtin_amdgcn_mfma_f32_16x16x32_bf16(afrag, bfrag, acc[mt], 0, 0, 0);
    }
  }
  #pragma unroll
  for (int mt = 0; mt < 8; ++mt) {
    #pragma unroll
    for (int r = 0; r < 4; ++r) {
      int c = mt * 16 + quad * 4 + r;
      size_t off = ((size_t)(b * DIMC + c) << 14) + p;
      outp[off] = acc[mt][r] + bp2[c] + xf[off];
    }
  }
}

extern "C" void kernel_launch(void* const* d_in, const int* in_sizes, int n_in,
                              void* d_out, int out_size, void* d_ws,
                              size_t ws_size, hipStream_t stream) {
  const float* x = (const float*)d_in[0];
  const float* ln1_g = (const float*)d_in[1];
  const float* ln1_b = (const float*)d_in[2];
  const float* w_qkv = (const float*)d_in[3];
  const float* w_out = (const float*)d_in[4];
  const float* b_out = (const float*)d_in[5];
  const float* ln2_g = (const float*)d_in[6];
  const float* ln2_b = (const float*)d_in[7];
  const float* w_p0 = (const float*)d_in[8];
  const float* b_p0 = (const float*)d_in[9];
  const float* dw_k = (const float*)d_in[10];
  const float* bn_g = (const float*)d_in[11];
  const float* bn_b = (const float*)d_in[12];
  const float* w_p2 = (const float*)d_in[13];
  const float* b_p2 = (const float*)d_in[14];
  float* outp = (float*)d_out;

  char* ws = (char*)d_ws;
  size_t off = 0;
  auto alloc = [&](size_t bytes) {
    void* p = ws + off;
    off += (bytes + 1023) & ~(size_t)1023;
    return p;
  };
  bfu* tok = (bfu*)alloc((size_t)NREG * DIMC * TT * 2);
  float* xf = (float*)alloc((size_t)BB * DIMC * HW * 4);
  bfu* xln = (bfu*)alloc((size_t)BB * DIMC * HW * 2);
  bfu* ym = (bfu*)alloc((size_t)BB * HID * HW * 2);
  bfu* ym2 = (bfu*)alloc((size_t)BB * HID * HW * 2);
  float* bnacc = (float*)alloc(2 * HID * 4);
  bfu* wqkvT = (bfu*)alloc(16 * 3072 * 2);
  bfu* ap0 = (bfu*)alloc(16 * 256 * 8 * 2);
  bfu* ap2 = (bfu*)alloc(32 * 128 * 8 * 2);
  bfu* awout = (bfu*)alloc(16 * 128 * 8 * 2);
  // overlays (lifetimes disjoint)
  bfu* o = ym;     // used k23->k4; ym written first in k6
  bfu* aln = ym2;  // used k1->k23; ym2 written first in k7

  // k1 grid: NREG gather blocks + 65 weight-prep blocks (former kprep)
  k1_gather<<<NREG + 65, 256, 0, stream>>>(x, ln1_g, ln1_b, tok, aln, w_qkv,
                                           w_p0, w_p2, w_out, wqkvT, ap0, ap2,
                                           awout, bnacc);
  k23_fused<<<dim3(NREG, NHEADS), 256, 0, stream>>>(aln, wqkvT, o);
  k4_outproj<<<dim3(NREG, 4), 256, 0, stream>>>(o, awout, b_out, tok);
  k5_merge<<<dim3(HH_, BB), 512, 0, stream>>>(tok, ln2_g, ln2_b, xf, xln);
  k6_p0<<<dim3(256, BB), 256, 0, stream>>>(xln, ap0, b_p0, ym);
  k7_conv<<<BB * HID, 256, 0, stream>>>(ym, dw_k, ym2, bnacc);
  k10_p2<<<dim3(256, BB), 256, 0, stream>>>(ym2, bnacc, bn_g, bn_b, ap2, b_p2,
                                            xf, outp);
}

// Round 18
// 309.549 us; speedup vs baseline: 1.2731x; 1.0534x over previous
//
#include <hip/hip_runtime.h>

#define DIMC 128
#define NHEADS 4
#define HD 32
#define HID 256
#define BB 4
#define HH_ 128
#define WW_ 128
#define HW 16384
#define RS 16
#define STEP 14
#define NR 9
#define NREGB 81
#define NREG 324
#define TT 256

typedef unsigned short bfu;  // bf16 bits
typedef __attribute__((ext_vector_type(8))) short bf16x8;
typedef __attribute__((ext_vector_type(4))) float f32x4;

__device__ __forceinline__ float bf2f(bfu u) {
  return __uint_as_float(((unsigned int)u) << 16);
}
// HW packed f32->bf16 (RNE): dst.lo16 = bf16(lo), dst.hi16 = bf16(hi).
// Semantics hardware-verified R11/R12.
__device__ __forceinline__ unsigned cvt_pk_bf16(float lo, float hi) {
  unsigned r;
  asm("v_cvt_pk_bf16_f32 %0, %1, %2" : "=v"(r) : "v"(lo), "v"(hi));
  return r;
}
// tanh-form gelu (R17-verified): ~8 branch-free VALU ops.
__device__ __forceinline__ float gelu_fast(float x) {
  float x2 = x * x;
  float z = x * fmaf(x2, 0.07135481627f, 1.5957691216f);
  float e = __expf(-z);
  return __fdividef(x, 1.0f + e);
}

// tok layout (R18): [reg][t][c] row-major (was [reg][c][t]).
// Row of 128 c's per token is contiguous -> vector IO in k1/k4/k5.

// K1: gather -> tok bf16 [reg][t][c]; aln bf16 blocked [reg][g=c/8][t][8c]
// Blocks >= NREG run the weight-prep tail:
//  pb 0..23 wqkvT; pb 24 zero bnacc; pb 25..40 ap0; pb 41..56 ap2;
//  pb 57..64 awout
__global__ __launch_bounds__(256) void k1_gather(
    const float* __restrict__ x, const float* __restrict__ g,
    const float* __restrict__ bia, bfu* __restrict__ tok,
    bfu* __restrict__ aln, const float* __restrict__ wqkv,
    const float* __restrict__ wp0, const float* __restrict__ wp2,
    const float* __restrict__ wout, bfu* __restrict__ wqkvT,
    bfu* __restrict__ ap0, bfu* __restrict__ ap2, bfu* __restrict__ awout,
    float* __restrict__ bnacc) {
  int bid = blockIdx.x;
  int tid = threadIdx.x;
  if (bid >= NREG) {
    int pb = bid - NREG;
    if (pb < 24) {
      int task = pb * 256 + tid;  // kg*384 + n
      int kg = task / 384, n = task % 384;
      float v[8];
      #pragma unroll
      for (int j = 0; j < 8; ++j) v[j] = wqkv[(kg * 8 + j) * 384 + n];
      uint4 pk = make_uint4(cvt_pk_bf16(v[0], v[1]), cvt_pk_bf16(v[2], v[3]),
                            cvt_pk_bf16(v[4], v[5]), cvt_pk_bf16(v[6], v[7]));
      *(uint4*)&wqkvT[(size_t)kg * 3072 + n * 8] = pk;
    } else if (pb == 24) {
      bnacc[tid] = 0.f;
      bnacc[256 + tid] = 0.f;
    } else if (pb < 41) {
      int task = (pb - 25) * 256 + tid;  // kg*256 + f
      int kg = task >> 8, f = task & 255;
      float v[8];
      #pragma unroll
      for (int j = 0; j < 8; ++j) v[j] = wp0[(kg * 8 + j) * 256 + f];
      uint4 pk = make_uint4(cvt_pk_bf16(v[0], v[1]), cvt_pk_bf16(v[2], v[3]),
                            cvt_pk_bf16(v[4], v[5]), cvt_pk_bf16(v[6], v[7]));
      *(uint4*)&ap0[((size_t)kg * 256 + f) * 8] = pk;
    } else if (pb < 57) {
      int task = (pb - 41) * 256 + tid;  // kg*128 + c
      int kg = task >> 7, c = task & 127;
      float v[8];
      #pragma unroll
      for (int j = 0; j < 8; ++j) v[j] = wp2[(kg * 8 + j) * 128 + c];
      uint4 pk = make_uint4(cvt_pk_bf16(v[0], v[1]), cvt_pk_bf16(v[2], v[3]),
                            cvt_pk_bf16(v[4], v[5]), cvt_pk_bf16(v[6], v[7]));
      *(uint4*)&ap2[((size_t)kg * 128 + c) * 8] = pk;
    } else {
      int task = (pb - 57) * 256 + tid;  // kg*128 + c
      int kg = task >> 7, c = task & 127;
      float v[8];
      #pragma unroll
      for (int j = 0; j < 8; ++j) v[j] = wout[(kg * 8 + j) * 128 + c];
      uint4 pk = make_uint4(cvt_pk_bf16(v[0], v[1]), cvt_pk_bf16(v[2], v[3]),
                            cvt_pk_bf16(v[4], v[5]), cvt_pk_bf16(v[6], v[7]));
      *(uint4*)&awout[((size_t)kg * 128 + c) * 8] = pk;
    }
    return;
  }
  int reg = bid;
  int b = reg / NREGB, ij = reg % NREGB;
  int i = ij / NR, j = ij % NR;
  int t = tid;
  int r = t >> 4, s = t & 15;
  int hh = i * STEP + r, ww = j * STEP + s;
  const float* xp = x + (size_t)b * DIMC * HW + (size_t)hh * WW_ + ww;
  bfu* tp = tok + (size_t)reg * DIMC * TT + (size_t)t * DIMC;  // [t][c] row
  float sum = 0.f, sq = 0.f;
  #pragma unroll 2
  for (int c8 = 0; c8 < DIMC; c8 += 8) {
    unsigned pks[4];
    #pragma unroll
    for (int jj = 0; jj < 4; ++jj) {
      float v0 = xp[(size_t)(c8 + 2 * jj) * HW];
      float v1 = xp[(size_t)(c8 + 2 * jj + 1) * HW];
      pks[jj] = cvt_pk_bf16(v0, v1);
      sum += v0 + v1;
      sq = fmaf(v0, v0, sq);
      sq = fmaf(v1, v1, sq);
    }
    *(uint4*)&tp[c8] = make_uint4(pks[0], pks[1], pks[2], pks[3]);
  }
  float mu = sum * (1.0f / DIMC);
  float var = sq * (1.0f / DIMC) - mu * mu;
  float rstd = rsqrtf(var + 1e-5f);
  bfu* ap = aln + (size_t)reg * 32768 + t * 8;
  #pragma unroll
  for (int gidx = 0; gidx < 16; ++gidx) {
    float y[8];
    #pragma unroll
    for (int jj = 0; jj < 8; ++jj) {
      int c = gidx * 8 + jj;
      float vv = xp[(size_t)c * HW];  // L2-hot re-read
      y[jj] = (vv - mu) * rstd * g[c] + bia[c];
    }
    uint4 pk = make_uint4(cvt_pk_bf16(y[0], y[1]), cvt_pk_bf16(y[2], y[3]),
                          cvt_pk_bf16(y[4], y[5]), cvt_pk_bf16(y[6], y[7]));
    *(uint4*)&ap[(size_t)gidx * 2048] = pk;
  }
}

// K23: fused per-(region,head) QKV projection + attention.
// R12-verified structure; all pack sites use cvt_pk. (No tok access.)
__global__ __launch_bounds__(256) void k23_fused(
    const bfu* __restrict__ aln, const bfu* __restrict__ wqkvT,
    bfu* __restrict__ o) {
  int reg = blockIdx.x;
  int h = blockIdx.y;
  __shared__ __align__(16) bfu sQ[256 * 40];        // [tok][d32 +8pad] 20.5KB
  __shared__ __align__(16) bfu sK[256 * 40];        // 20.5KB
  __shared__ __align__(16) bfu vperm[8 * 4 * 264];  // 16.9KB
  int tid = threadIdx.x;
  int wave = tid >> 6, lane = tid & 63;
  int quad = lane >> 4, n16 = lane & 15;

  // ---- QKV GEMM for this head: [256 tok x 96 cols] = aln @ W[:, cols(h)]
  const bfu* ab = aln + (size_t)reg * 32768 + (wave * 64 + n16) * 8;
  int colb[6];
  colb[0] = h * 32;        // q lo
  colb[1] = h * 32 + 16;   // q hi
  colb[2] = 128 + h * 32;  // k lo
  colb[3] = 144 + h * 32;  // k hi
  colb[4] = 256 + h * 32;  // v lo
  colb[5] = 272 + h * 32;  // v hi
  f32x4 acc[4][6];
  #pragma unroll
  for (int m = 0; m < 4; ++m)
    #pragma unroll
    for (int nt = 0; nt < 6; ++nt) acc[m][nt] = (f32x4){0.f, 0.f, 0.f, 0.f};
  #pragma unroll
  for (int ph = 0; ph < 4; ++ph) {
    int gg = ph * 4 + quad;
    bf16x8 af[4];
    #pragma unroll
    for (int m = 0; m < 4; ++m)
      af[m] = *(const bf16x8*)&ab[(size_t)gg * 2048 + m * 128];
    const bfu* bgg = wqkvT + (size_t)gg * 3072;
    bf16x8 bfr[6];
    #pragma unroll
    for (int nt = 0; nt < 6; ++nt)
      bfr[nt] = *(const bf16x8*)&bgg[(colb[nt] + n16) * 8];
    #pragma unroll
    for (int m = 0; m < 4; ++m)
      #pragma unroll
      for (int nt = 0; nt < 6; ++nt)
        acc[m][nt] =
            __builtin_amdgcn_mfma_f32_16x16x32_bf16(af[m], bfr[nt], acc[m][nt], 0, 0, 0);
  }
  // ---- scatter acc -> LDS (C/D map: row = quad*4+r, col = n16)
  // token t = wave*64 + m*16 + quad*4 + r; addressing identical to R11/R12.
  #pragma unroll
  for (int m = 0; m < 4; ++m) {
    int g = wave * 2 + (m >> 1);
    int jt = (m & 1) * 4;
    int T0 = wave * 64 + m * 16 + quad * 4;
    unsigned q00 = cvt_pk_bf16(acc[m][0][0], acc[m][0][1]);
    unsigned q01 = cvt_pk_bf16(acc[m][0][2], acc[m][0][3]);
    unsigned q10 = cvt_pk_bf16(acc[m][1][0], acc[m][1][1]);
    unsigned q11 = cvt_pk_bf16(acc[m][1][2], acc[m][1][3]);
    unsigned k00 = cvt_pk_bf16(acc[m][2][0], acc[m][2][1]);
    unsigned k01 = cvt_pk_bf16(acc[m][2][2], acc[m][2][3]);
    unsigned k10 = cvt_pk_bf16(acc[m][3][0], acc[m][3][1]);
    unsigned k11 = cvt_pk_bf16(acc[m][3][2], acc[m][3][3]);
    sQ[(T0 + 0) * 40 + n16] = (bfu)q00;
    sQ[(T0 + 1) * 40 + n16] = (bfu)(q00 >> 16);
    sQ[(T0 + 2) * 40 + n16] = (bfu)q01;
    sQ[(T0 + 3) * 40 + n16] = (bfu)(q01 >> 16);
    sQ[(T0 + 0) * 40 + 16 + n16] = (bfu)q10;
    sQ[(T0 + 1) * 40 + 16 + n16] = (bfu)(q10 >> 16);
    sQ[(T0 + 2) * 40 + 16 + n16] = (bfu)q11;
    sQ[(T0 + 3) * 40 + 16 + n16] = (bfu)(q11 >> 16);
    sK[(T0 + 0) * 40 + n16] = (bfu)k00;
    sK[(T0 + 1) * 40 + n16] = (bfu)(k00 >> 16);
    sK[(T0 + 2) * 40 + n16] = (bfu)k01;
    sK[(T0 + 3) * 40 + n16] = (bfu)(k01 >> 16);
    sK[(T0 + 0) * 40 + 16 + n16] = (bfu)k10;
    sK[(T0 + 1) * 40 + 16 + n16] = (bfu)(k10 >> 16);
    sK[(T0 + 2) * 40 + 16 + n16] = (bfu)k11;
    sK[(T0 + 3) * 40 + 16 + n16] = (bfu)(k11 >> 16);
    unsigned v0 = cvt_pk_bf16(acc[m][4][0], acc[m][4][1]);
    unsigned v1 = cvt_pk_bf16(acc[m][4][2], acc[m][4][3]);
    unsigned v2 = cvt_pk_bf16(acc[m][5][0], acc[m][5][1]);
    unsigned v3 = cvt_pk_bf16(acc[m][5][2], acc[m][5][3]);
    int vbase = (g * 4 + quad) * 264 + jt;
    *(uint2*)&vperm[vbase + n16 * 8] = make_uint2(v0, v1);
    *(uint2*)&vperm[vbase + (16 + n16) * 8] = make_uint2(v2, v3);
  }
  __syncthreads();

  // ---- attention (R12-verified body) ----
  const f32x4 zero = {0.f, 0.f, 0.f, 0.f};
  const float scale = 0.17677669529663687f;  // 1/sqrt(32)
  for (int mi = 0; mi < 4; ++mi) {
    int mt = wave * 4 + mi;
    bf16x8 qf = *(const bf16x8*)&sQ[(mt * 16 + n16) * 40 + quad * 8];
    f32x4 st[16];
    #pragma unroll
    for (int T = 0; T < 16; ++T) {
      bf16x8 kf = *(const bf16x8*)&sK[(T * 16 + n16) * 40 + quad * 8];
      st[T] = __builtin_amdgcn_mfma_f32_16x16x32_bf16(kf, qf, zero, 0, 0, 0);
    }
    float m = st[0][0];
    #pragma unroll
    for (int T = 0; T < 16; ++T)
      #pragma unroll
      for (int r = 0; r < 4; ++r) m = fmaxf(m, st[T][r]);
    m = fmaxf(m, __shfl_xor(m, 16, 64));
    m = fmaxf(m, __shfl_xor(m, 32, 64));
    float l = 0.f;
    #pragma unroll
    for (int T = 0; T < 16; ++T)
      #pragma unroll
      for (int r = 0; r < 4; ++r) {
        float p = __expf((st[T][r] - m) * scale);
        st[T][r] = p;
        l += p;
      }
    l += __shfl_xor(l, 16, 64);
    l += __shfl_xor(l, 32, 64);
    float inv = 1.0f / l;
    f32x4 oa0 = zero, oa1 = zero;
    #pragma unroll
    for (int g = 0; g < 8; ++g) {
      uint4 pw = make_uint4(cvt_pk_bf16(st[2 * g][0], st[2 * g][1]),
                            cvt_pk_bf16(st[2 * g][2], st[2 * g][3]),
                            cvt_pk_bf16(st[2 * g + 1][0], st[2 * g + 1][1]),
                            cvt_pk_bf16(st[2 * g + 1][2], st[2 * g + 1][3]));
      bf16x8 pf = *(bf16x8*)&pw;
      bf16x8 va = *(const bf16x8*)&vperm[(g * 4 + quad) * 264 + n16 * 8];
      bf16x8 vb = *(const bf16x8*)&vperm[(g * 4 + quad) * 264 + (16 + n16) * 8];
      oa0 = __builtin_amdgcn_mfma_f32_16x16x32_bf16(va, pf, oa0, 0, 0, 0);
      oa1 = __builtin_amdgcn_mfma_f32_16x16x32_bf16(vb, pf, oa1, 0, 0, 0);
    }
    bfu* ob = o + ((size_t)reg * 256 + mt * 16 + n16) * 128 + h * 32 + quad * 4;
    unsigned o0 = cvt_pk_bf16(oa0[0] * inv, oa0[1] * inv);
    unsigned o1 = cvt_pk_bf16(oa0[2] * inv, oa0[3] * inv);
    unsigned o2 = cvt_pk_bf16(oa1[0] * inv, oa1[1] * inv);
    unsigned o3 = cvt_pk_bf16(oa1[2] * inv, oa1[3] * inv);
    *(uint2*)&ob[0] = make_uint2(o0, o1);
    *(uint2*)&ob[16] = make_uint2(o2, o3);
  }
}

// K4: tok[t][c] (bf16) += o @ w_out + b_out via MFMA, LDS-free.
// R18: tok RMW is contiguous 4B pairs (was 512B-strided 2B).
__global__ __launch_bounds__(256) void k4_outproj(
    const bfu* __restrict__ o, const bfu* __restrict__ awout,
    const float* __restrict__ bout, bfu* __restrict__ tok) {
  int reg = blockIdx.x;
  int tt = blockIdx.y;
  int tid = threadIdx.x;
  int wave = tid >> 6, lane = tid & 63;
  int quad = lane >> 4, n16 = lane & 15;
  int t = tt * 64 + wave * 16 + n16;
  const bfu* ob = o + ((size_t)reg * 256 + t) * 128;
  f32x4 acc[8];
  #pragma unroll
  for (int mt = 0; mt < 8; ++mt) acc[mt] = (f32x4){0.f, 0.f, 0.f, 0.f};
  #pragma unroll
  for (int kt = 0; kt < 4; ++kt) {
    bf16x8 bfrag = *(const bf16x8*)&ob[kt * 32 + quad * 8];
    const bfu* arow = awout + ((size_t)(kt * 4 + quad) * 128 + n16) * 8;
    #pragma unroll
    for (int mt = 0; mt < 8; ++mt) {
      bf16x8 afrag = *(const bf16x8*)&arow[mt * 128];
      acc[mt] = __builtin_amdgcn_mfma_f32_16x16x32_bf16(afrag, bfrag, acc[mt], 0, 0, 0);
    }
  }
  bfu* tokr = tok + (size_t)reg * DIMC * TT + (size_t)t * DIMC;  // [t][c] row
  #pragma unroll
  for (int mt = 0; mt < 8; ++mt) {
    #pragma unroll
    for (int rp = 0; rp < 2; ++rp) {
      int c = mt * 16 + quad * 4 + rp * 2;
      unsigned old = *(const unsigned*)&tokr[c];
      float v0 = bf2f((bfu)old) + acc[mt][rp * 2] + bout[c];
      float v1 = bf2f((bfu)(old >> 16)) + acc[mt][rp * 2 + 1] + bout[c + 1];
      *(unsigned*)&tokr[c] = cvt_pk_bf16(v0, v1);
    }
  }
}

// K5: overlap merge (bf16 tok [reg][t][c]) -> xf fp32 + xln bf16 blocked.
// R18: uint4 row reads (was 512B-strided scalar 2B gather).
__global__ __launch_bounds__(512) void k5_merge(
    const bfu* __restrict__ tok, const float* __restrict__ ln2g,
    const float* __restrict__ ln2b, float* __restrict__ xf,
    bfu* __restrict__ xln) {
  int hh = blockIdx.x, b = blockIdx.y;
  int tid = threadIdx.x;
  int w = tid & 127, q = tid >> 7;
  int ilo = (hh >= 2) ? (hh - 2) / 14 : 0;
  int ihi = hh / 14;
  if (ihi > 8) ihi = 8;
  int jlo = (w >= 2) ? (w - 2) / 14 : 0;
  int jhi = w / 14;
  if (jhi > 8) jhi = 8;
  float rcnt = 1.0f / (float)((ihi - ilo + 1) * (jhi - jlo + 1));
  size_t offs[4];
  int nij = 0;
  for (int i = ilo; i <= ihi; ++i)
    for (int j = jlo; j <= jhi; ++j) {
      int reg = b * NREGB + i * NR + j;
      int r = hh - i * STEP, s = w - j * STEP;
      offs[nij++] = (size_t)reg * DIMC * TT + (size_t)(r * 16 + s) * DIMC;
    }
  float* xp = xf + ((size_t)b * DIMC << 14) + hh * WW_ + w;
  float mm[32];
  float sum = 0.f, sq = 0.f;
  int c0 = q * 32;
  #pragma unroll
  for (int gl = 0; gl < 4; ++gl) {
    int cb = c0 + gl * 8;
    float v[8];
    #pragma unroll
    for (int jj = 0; jj < 8; ++jj) v[jj] = 0.f;
    for (int k = 0; k < nij; ++k) {
      uint4 u = *(const uint4*)&tok[offs[k] + cb];
      v[0] += bf2f((bfu)u.x);
      v[1] += bf2f((bfu)(u.x >> 16));
      v[2] += bf2f((bfu)u.y);
      v[3] += bf2f((bfu)(u.y >> 16));
      v[4] += bf2f((bfu)u.z);
      v[5] += bf2f((bfu)(u.z >> 16));
      v[6] += bf2f((bfu)u.w);
      v[7] += bf2f((bfu)(u.w >> 16));
    }
    #pragma unroll
    for (int jj = 0; jj < 8; ++jj) {
      float m = v[jj] * rcnt;
      xp[(size_t)(cb + jj) << 14] = m;
      mm[gl * 8 + jj] = m;
      sum += m;
      sq = fmaf(m, m, sq);
    }
  }
  __shared__ float rs[512];
  __shared__ float rq[512];
  __shared__ float muS[128];
  __shared__ float rsdS[128];
  rs[tid] = sum;
  rq[tid] = sq;
  __syncthreads();
  if (tid < 128) {
    float s4 = rs[tid] + rs[tid + 128] + rs[tid + 256] + rs[tid + 384];
    float q4 = rq[tid] + rq[tid + 128] + rq[tid + 256] + rq[tid + 384];
    float mu = s4 * (1.0f / DIMC);
    float var = q4 * (1.0f / DIMC) - mu * mu;
    muS[tid] = mu;
    rsdS[tid] = rsqrtf(var + 1e-5f);
  }
  __syncthreads();
  float mu = muS[w], rstd = rsdS[w];
  int p = hh * WW_ + w;
  #pragma unroll
  for (int gl = 0; gl < 4; ++gl) {
    int gidx = q * 4 + gl;
    float y[8];
    #pragma unroll
    for (int j = 0; j < 8; ++j) {
      int c = gidx * 8 + j;
      y[j] = (mm[gl * 8 + j] - mu) * rstd * ln2g[c] + ln2b[c];
    }
    uint4 pk = make_uint4(cvt_pk_bf16(y[0], y[1]), cvt_pk_bf16(y[2], y[3]),
                          cvt_pk_bf16(y[4], y[5]), cvt_pk_bf16(y[6], y[7]));
    *(uint4*)&xln[(((size_t)(b * 16 + gidx) << 14) + p) * 8] = pk;
  }
}

// K6: ym[b][f][p] = xln @ w_p0 + b_p0 via MFMA
__global__ __launch_bounds__(256) void k6_p0(
    const bfu* __restrict__ xln, const bfu* __restrict__ ap0,
    const float* __restrict__ bp0, bfu* __restrict__ ym) {
  int b = blockIdx.y;
  int ptile = blockIdx.x * 64;
  int tid = threadIdx.x;
  int wv = tid >> 6, lane = tid & 63;
  int quad = lane >> 4, n16 = lane & 15;
  int p = ptile + wv * 16 + n16;
  f32x4 acc[16];
  #pragma unroll
  for (int mt = 0; mt < 16; ++mt) acc[mt] = (f32x4){0.f, 0.f, 0.f, 0.f};
  #pragma unroll
  for (int ph = 0; ph < 4; ++ph) {
    int gg = ph * 4 + quad;
    bf16x8 bfrag = *(const bf16x8*)&xln[(((size_t)(b * 16 + gg) << 14) + p) * 8];
    const bfu* arow = ap0 + ((size_t)gg * 256 + n16) * 8;
    #pragma unroll
    for (int mt = 0; mt < 16; ++mt) {
      bf16x8 afrag = *(const bf16x8*)&arow[mt * 128];
      acc[mt] = __builtin_amdgcn_mfma_f32_16x16x32_bf16(afrag, bfrag, acc[mt], 0, 0, 0);
    }
  }
  #pragma unroll
  for (int mt = 0; mt < 16; ++mt) {
    #pragma unroll
    for (int rp = 0; rp < 2; ++rp) {
      int f = mt * 16 + quad * 4 + rp * 2;
      float v0 = acc[mt][rp * 2] + bp0[f];
      float v1 = acc[mt][rp * 2 + 1] + bp0[f + 1];
      unsigned pk = cvt_pk_bf16(v0, v1);
      ym[((size_t)(b * HID + f) << 14) + p] = (bfu)pk;
      ym[((size_t)(b * HID + f + 1) << 14) + p] = (bfu)(pk >> 16);
    }
  }
}

// K7: 5x5 depthwise conv, whole plane in LDS, fused BN partials
__global__ __launch_bounds__(256) void k7_conv(
    const bfu* __restrict__ ym, const float* __restrict__ dwk,
    bfu* __restrict__ ym2, float* __restrict__ bnacc) {
  int bf = blockIdx.x;
  int f = bf & (HID - 1);
  __shared__ bfu sp[128 * 134];
  const bfu* in = ym + ((size_t)bf << 14);
  int tid = threadIdx.x;
  for (int idx = tid; idx < 2048; idx += 256) {
    int r = idx >> 4, c8 = (idx & 15) << 3;
    ushort4 a = *(const ushort4*)&in[(r << 7) + c8];
    ushort4 b = *(const ushort4*)&in[(r << 7) + c8 + 4];
    bfu* d = &sp[r * 134 + c8];
    d[0] = a.x; d[1] = a.y; d[2] = a.z; d[3] = a.w;
    d[4] = b.x; d[5] = b.y; d[6] = b.z; d[7] = b.w;
  }
  float wk[25];
  #pragma unroll
  for (int i = 0; i < 25; ++i) wk[i] = dwk[f * 25 + i];
  __syncthreads();
  int row = tid >> 1, half = (tid & 1) << 6;
  float acc[64];
  #pragma unroll
  for (int i = 0; i < 64; ++i) acc[i] = 0.f;
  #pragma unroll
  for (int ky = 0; ky < 5; ++ky) {
    int y = row + ky - 2;
    if (y < 0 || y >= 128) continue;
    const bfu* rp = &sp[y * 134];
    float win[68];
    #pragma unroll
    for (int c = 0; c < 68; ++c) {
      int cc = half + c - 2;
      win[c] = (cc >= 0 && cc < 128) ? bf2f(rp[cc]) : 0.f;
    }
    #pragma unroll
    for (int kx = 0; kx < 5; ++kx) {
      float wv = wk[ky * 5 + kx];
      #pragma unroll
      for (int i = 0; i < 64; ++i) acc[i] = fmaf(win[i + kx], wv, acc[i]);
    }
  }
  float s = 0.f, sq = 0.f;
  #pragma unroll
  for (int i = 0; i < 64; ++i) {
    s += acc[i];
    sq = fmaf(acc[i], acc[i], sq);
  }
  bfu* op = ym2 + ((size_t)bf << 14) + (row << 7) + half;
  #pragma unroll
  for (int g8 = 0; g8 < 8; ++g8) {
    uint4 pk = make_uint4(cvt_pk_bf16(acc[g8 * 8 + 0], acc[g8 * 8 + 1]),
                          cvt_pk_bf16(acc[g8 * 8 + 2], acc[g8 * 8 + 3]),
                          cvt_pk_bf16(acc[g8 * 8 + 4], acc[g8 * 8 + 5]),
                          cvt_pk_bf16(acc[g8 * 8 + 6], acc[g8 * 8 + 7]));
    *(uint4*)&op[g8 * 8] = pk;
  }
  __syncthreads();
  float* red = (float*)sp;
  red[tid] = s;
  red[256 + tid] = sq;
  __syncthreads();
  for (int o = 128; o > 0; o >>= 1) {
    if (tid < o) {
      red[tid] += red[tid + o];
      red[256 + tid] += red[256 + tid + o];
    }
    __syncthreads();
  }
  if (tid == 0) {
    atomicAdd(&bnacc[f], red[0]);
    atomicAdd(&bnacc[HID + f], red[256]);
  }
}

// K10: out = gelu(gelu(bn(ym2))) @ w_p2 + b_p2 + xf via MFMA.
// BN finalize folded into a block prologue; gelu_fast (R17-verified).
__global__ __launch_bounds__(256) void k10_p2(
    const bfu* __restrict__ ym2, const float* __restrict__ bnacc,
    const float* __restrict__ bng, const float* __restrict__ bnb,
    const bfu* __restrict__ ap2, const float* __restrict__ bp2,
    const float* __restrict__ xf, float* __restrict__ outp) {
  int b = blockIdx.y;
  int ptile = blockIdx.x * 64;
  int tid = threadIdx.x;
  __shared__ float sA[HID];
  __shared__ float sB[HID];
  {
    float mu = bnacc[tid] * (1.0f / 65536.f);
    float var = bnacc[HID + tid] * (1.0f / 65536.f) - mu * mu;
    float sa = rsqrtf(var + 1e-5f) * bng[tid];
    sA[tid] = sa;
    sB[tid] = bnb[tid] - mu * sa;
  }
  __syncthreads();
  int wv = tid >> 6, lane = tid & 63;
  int quad = lane >> 4, n16 = lane & 15;
  int p = ptile + wv * 16 + n16;
  f32x4 acc[8];
  #pragma unroll
  for (int mt = 0; mt < 8; ++mt) acc[mt] = (f32x4){0.f, 0.f, 0.f, 0.f};
  #pragma unroll
  for (int ph = 0; ph < 8; ++ph) {
    int gg = ph * 4 + quad;
    const bfu* ymp = ym2 + (((size_t)(b * HID + gg * 8)) << 14) + p;
    float vals[8];
    #pragma unroll
    for (int j = 0; j < 8; ++j) vals[j] = bf2f(ymp[(size_t)j << 14]);
    float gv[8];
    #pragma unroll
    for (int j = 0; j < 8; ++j) {
      float v = fmaf(vals[j], sA[gg * 8 + j], sB[gg * 8 + j]);
      gv[j] = gelu_fast(gelu_fast(v));
    }
    uint4 pk = make_uint4(cvt_pk_bf16(gv[0], gv[1]), cvt_pk_bf16(gv[2], gv[3]),
                          cvt_pk_bf16(gv[4], gv[5]), cvt_pk_bf16(gv[6], gv[7]));
    bf16x8 bfrag = *(bf16x8*)&pk;
    const bfu* arow = ap2 + ((size_t)gg * 128 + n16) * 8;
    #pragma unroll
    for (int mt = 0; mt < 8; ++mt) {
      bf16x8 afrag = *(const bf16x8*)&arow[mt * 128];
      acc[mt] = __builtin_amdgcn_mfma_f32_16x16x32_bf16(afrag, bfrag, acc[mt], 0, 0, 0);
    }
  }
  #pragma unroll
  for (int mt = 0; mt < 8; ++mt) {
    #pragma unroll
    for (int r = 0; r < 4; ++r) {
      int c = mt * 16 + quad * 4 + r;
      size_t off = ((size_t)(b * DIMC + c) << 14) + p;
      outp[off] = acc[mt][r] + bp2[c] + xf[off];
    }
  }
}

extern "C" void kernel_launch(void* const* d_in, const int* in_sizes, int n_in,
                              void* d_out, int out_size, void* d_ws,
                              size_t ws_size, hipStream_t stream) {
  const float* x = (const float*)d_in[0];
  const float* ln1_g = (const float*)d_in[1];
  const float* ln1_b = (const float*)d_in[2];
  const float* w_qkv = (const float*)d_in[3];
  const float* w_out = (const float*)d_in[4];
  const float* b_out = (const float*)d_in[5];
  const float* ln2_g = (const float*)d_in[6];
  const float* ln2_b = (const float*)d_in[7];
  const float* w_p0 = (const float*)d_in[8];
  const float* b_p0 = (const float*)d_in[9];
  const float* dw_k = (const float*)d_in[10];
  const float* bn_g = (const float*)d_in[11];
  const float* bn_b = (const float*)d_in[12];
  const float* w_p2 = (const float*)d_in[13];
  const float* b_p2 = (const float*)d_in[14];
  float* outp = (float*)d_out;

  char* ws = (char*)d_ws;
  size_t off = 0;
  auto alloc = [&](size_t bytes) {
    void* p = ws + off;
    off += (bytes + 1023) & ~(size_t)1023;
    return p;
  };
  bfu* tok = (bfu*)alloc((size_t)NREG * DIMC * TT * 2);
  float* xf = (float*)alloc((size_t)BB * DIMC * HW * 4);
  bfu* xln = (bfu*)alloc((size_t)BB * DIMC * HW * 2);
  bfu* ym = (bfu*)alloc((size_t)BB * HID * HW * 2);
  bfu* ym2 = (bfu*)alloc((size_t)BB * HID * HW * 2);
  float* bnacc = (float*)alloc(2 * HID * 4);
  bfu* wqkvT = (bfu*)alloc(16 * 3072 * 2);
  bfu* ap0 = (bfu*)alloc(16 * 256 * 8 * 2);
  bfu* ap2 = (bfu*)alloc(32 * 128 * 8 * 2);
  bfu* awout = (bfu*)alloc(16 * 128 * 8 * 2);
  // overlays (lifetimes disjoint)
  bfu* o = ym;     // used k23->k4; ym written first in k6
  bfu* aln = ym2;  // used k1->k23; ym2 written first in k7

  // k1 grid: NREG gather blocks + 65 weight-prep blocks (former kprep)
  k1_gather<<<NREG + 65, 256, 0, stream>>>(x, ln1_g, ln1_b, tok, aln, w_qkv,
                                           w_p0, w_p2, w_out, wqkvT, ap0, ap2,
                                           awout, bnacc);
  k23_fused<<<dim3(NREG, NHEADS), 256, 0, stream>>>(aln, wqkvT, o);
  k4_outproj<<<dim3(NREG, 4), 256, 0, stream>>>(o, awout, b_out, tok);
  k5_merge<<<dim3(HH_, BB), 512, 0, stream>>>(tok, ln2_g, ln2_b, xf, xln);
  k6_p0<<<dim3(256, BB), 256, 0, stream>>>(xln, ap0, b_p0, ym);
  k7_conv<<<BB * HID, 256, 0, stream>>>(ym, dw_k, ym2, bnacc);
  k10_p2<<<dim3(256, BB), 256, 0, stream>>>(ym2, bnacc, bn_g, bn_b, ap2, b_p2,
                                            xf, outp);
}

// Round 22
// 289.381 us; speedup vs baseline: 1.3619x; 1.0697x over previous
//
#include <hip/hip_runtime.h>

#define DIMC 128
#define NHEADS 4
#define HD 32
#define HID 256
#define BB 4
#define HH_ 128
#define WW_ 128
#define HW 16384
#define RS 16
#define STEP 14
#define NR 9
#define NREGB 81
#define NREG 324
#define TT 256

typedef unsigned short bfu;  // bf16 bits
typedef __attribute__((ext_vector_type(8))) short bf16x8;
typedef __attribute__((ext_vector_type(4))) float f32x4;

__device__ __forceinline__ float bf2f(bfu u) {
  return __uint_as_float(((unsigned int)u) << 16);
}
// HW packed f32->bf16 (RNE): dst.lo16 = bf16(lo), dst.hi16 = bf16(hi).
// Semantics hardware-verified R11/R12.
__device__ __forceinline__ unsigned cvt_pk_bf16(float lo, float hi) {
  unsigned r;
  asm("v_cvt_pk_bf16_f32 %0, %1, %2" : "=v"(r) : "v"(lo), "v"(hi));
  return r;
}
// tanh-form gelu (R17-verified): ~8 branch-free VALU ops.
__device__ __forceinline__ float gelu_fast(float x) {
  float x2 = x * x;
  float z = x * fmaf(x2, 0.07135481627f, 1.5957691216f);
  float e = __expf(-z);
  return __fdividef(x, 1.0f + e);
}

// K1 (R19): 512-thread blocks; 2 threads per token split the 128 channels.
// Each thread loads its 64 channels of x ONCE into registers (no re-read),
// LDS-combines LN partial sums across the half-pair, writes tok [reg][t][c]
// and its 8 aln groups from registers. Weight-prep tail on tid<256.
__global__ __launch_bounds__(512) void k1_gather(
    const float* __restrict__ x, const float* __restrict__ g,
    const float* __restrict__ bia, bfu* __restrict__ tok,
    bfu* __restrict__ aln, const float* __restrict__ wqkv,
    const float* __restrict__ wp0, const float* __restrict__ wp2,
    const float* __restrict__ wout, bfu* __restrict__ wqkvT,
    bfu* __restrict__ ap0, bfu* __restrict__ ap2, bfu* __restrict__ awout,
    float* __restrict__ bnacc) {
  int bid = blockIdx.x;
  int tid = threadIdx.x;
  if (bid >= NREG) {
    if (tid >= 256) return;
    int pb = bid - NREG;
    if (pb < 24) {
      int task = pb * 256 + tid;  // kg*384 + n
      int kg = task / 384, n = task % 384;
      float v[8];
      #pragma unroll
      for (int j = 0; j < 8; ++j) v[j] = wqkv[(kg * 8 + j) * 384 + n];
      uint4 pk = make_uint4(cvt_pk_bf16(v[0], v[1]), cvt_pk_bf16(v[2], v[3]),
                            cvt_pk_bf16(v[4], v[5]), cvt_pk_bf16(v[6], v[7]));
      *(uint4*)&wqkvT[(size_t)kg * 3072 + n * 8] = pk;
    } else if (pb == 24) {
      bnacc[tid] = 0.f;
      bnacc[256 + tid] = 0.f;
    } else if (pb < 41) {
      int task = (pb - 25) * 256 + tid;  // kg*256 + f
      int kg = task >> 8, f = task & 255;
      float v[8];
      #pragma unroll
      for (int j = 0; j < 8; ++j) v[j] = wp0[(kg * 8 + j) * 256 + f];
      uint4 pk = make_uint4(cvt_pk_bf16(v[0], v[1]), cvt_pk_bf16(v[2], v[3]),
                            cvt_pk_bf16(v[4], v[5]), cvt_pk_bf16(v[6], v[7]));
      *(uint4*)&ap0[((size_t)kg * 256 + f) * 8] = pk;
    } else if (pb < 57) {
      int task = (pb - 41) * 256 + tid;  // kg*128 + c
      int kg = task >> 7, c = task & 127;
      float v[8];
      #pragma unroll
      for (int j = 0; j < 8; ++j) v[j] = wp2[(kg * 8 + j) * 128 + c];
      uint4 pk = make_uint4(cvt_pk_bf16(v[0], v[1]), cvt_pk_bf16(v[2], v[3]),
                            cvt_pk_bf16(v[4], v[5]), cvt_pk_bf16(v[6], v[7]));
      *(uint4*)&ap2[((size_t)kg * 128 + c) * 8] = pk;
    } else {
      int task = (pb - 57) * 256 + tid;  // kg*128 + c
      int kg = task >> 7, c = task & 127;
      float v[8];
      #pragma unroll
      for (int j = 0; j < 8; ++j) v[j] = wout[(kg * 8 + j) * 128 + c];
      uint4 pk = make_uint4(cvt_pk_bf16(v[0], v[1]), cvt_pk_bf16(v[2], v[3]),
                            cvt_pk_bf16(v[4], v[5]), cvt_pk_bf16(v[6], v[7]));
      *(uint4*)&awout[((size_t)kg * 128 + c) * 8] = pk;
    }
    return;
  }
  int reg = bid;
  int b = reg / NREGB, ij = reg % NREGB;
  int i = ij / NR, j = ij % NR;
  int t = tid & 255;   // token
  int hf = tid >> 8;   // channel half
  int c0 = hf * 64;
  int r = t >> 4, s = t & 15;
  int hh = i * STEP + r, ww = j * STEP + s;
  const float* xp =
      x + (size_t)b * DIMC * HW + (size_t)c0 * HW + (size_t)hh * WW_ + ww;
  // load own 64 channels once into registers; accumulate LN partials
  float v[64];
  float sum = 0.f, sq = 0.f;
  #pragma unroll
  for (int c = 0; c < 64; ++c) {
    float vv = xp[(size_t)c * HW];
    v[c] = vv;
    sum += vv;
    sq = fmaf(vv, vv, sq);
  }
  __shared__ float rsum[512];
  __shared__ float rsq[512];
  rsum[tid] = sum;
  rsq[tid] = sq;
  __syncthreads();
  float tsum = rsum[t] + rsum[t + 256];
  float tsq = rsq[t] + rsq[t + 256];
  float mu = tsum * (1.0f / DIMC);
  float var = tsq * (1.0f / DIMC) - mu * mu;
  float rstd = rsqrtf(var + 1e-5f);
  // tok write: own half-row [t][c0..c0+64), 8 x uint4
  bfu* tp = tok + (size_t)reg * DIMC * TT + (size_t)t * DIMC + c0;
  #pragma unroll
  for (int g8 = 0; g8 < 8; ++g8) {
    uint4 pk = make_uint4(cvt_pk_bf16(v[g8 * 8 + 0], v[g8 * 8 + 1]),
                          cvt_pk_bf16(v[g8 * 8 + 2], v[g8 * 8 + 3]),
                          cvt_pk_bf16(v[g8 * 8 + 4], v[g8 * 8 + 5]),
                          cvt_pk_bf16(v[g8 * 8 + 6], v[g8 * 8 + 7]));
    *(uint4*)&tp[g8 * 8] = pk;
  }
  // aln write: own 8 groups (gidx = hf*8 + gl), from registers
  bfu* ap = aln + (size_t)reg * 32768 + t * 8;
  #pragma unroll
  for (int gl = 0; gl < 8; ++gl) {
    int gidx = hf * 8 + gl;
    float y[8];
    #pragma unroll
    for (int jj = 0; jj < 8; ++jj) {
      int c = gidx * 8 + jj;
      y[jj] = (v[gl * 8 + jj] - mu) * rstd * g[c] + bia[c];
    }
    uint4 pk = make_uint4(cvt_pk_bf16(y[0], y[1]), cvt_pk_bf16(y[2], y[3]),
                          cvt_pk_bf16(y[4], y[5]), cvt_pk_bf16(y[6], y[7]));
    *(uint4*)&ap[(size_t)gidx * 2048] = pk;
  }
}

// K23: fused per-(region,head) QKV projection + attention.
// R12-verified structure; all pack sites use cvt_pk. (No tok access.)
__global__ __launch_bounds__(256) void k23_fused(
    const bfu* __restrict__ aln, const bfu* __restrict__ wqkvT,
    bfu* __restrict__ o) {
  int reg = blockIdx.x;
  int h = blockIdx.y;
  __shared__ __align__(16) bfu sQ[256 * 40];        // [tok][d32 +8pad] 20.5KB
  __shared__ __align__(16) bfu sK[256 * 40];        // 20.5KB
  __shared__ __align__(16) bfu vperm[8 * 4 * 264];  // 16.9KB
  int tid = threadIdx.x;
  int wave = tid >> 6, lane = tid & 63;
  int quad = lane >> 4, n16 = lane & 15;

  // ---- QKV GEMM for this head: [256 tok x 96 cols] = aln @ W[:, cols(h)]
  const bfu* ab = aln + (size_t)reg * 32768 + (wave * 64 + n16) * 8;
  int colb[6];
  colb[0] = h * 32;        // q lo
  colb[1] = h * 32 + 16;   // q hi
  colb[2] = 128 + h * 32;  // k lo
  colb[3] = 144 + h * 32;  // k hi
  colb[4] = 256 + h * 32;  // v lo
  colb[5] = 272 + h * 32;  // v hi
  f32x4 acc[4][6];
  #pragma unroll
  for (int m = 0; m < 4; ++m)
    #pragma unroll
    for (int nt = 0; nt < 6; ++nt) acc[m][nt] = (f32x4){0.f, 0.f, 0.f, 0.f};
  #pragma unroll
  for (int ph = 0; ph < 4; ++ph) {
    int gg = ph * 4 + quad;
    bf16x8 af[4];
    #pragma unroll
    for (int m = 0; m < 4; ++m)
      af[m] = *(const bf16x8*)&ab[(size_t)gg * 2048 + m * 128];
    const bfu* bgg = wqkvT + (size_t)gg * 3072;
    bf16x8 bfr[6];
    #pragma unroll
    for (int nt = 0; nt < 6; ++nt)
      bfr[nt] = *(const bf16x8*)&bgg[(colb[nt] + n16) * 8];
    #pragma unroll
    for (int m = 0; m < 4; ++m)
      #pragma unroll
      for (int nt = 0; nt < 6; ++nt)
        acc[m][nt] =
            __builtin_amdgcn_mfma_f32_16x16x32_bf16(af[m], bfr[nt], acc[m][nt], 0, 0, 0);
  }
  // ---- scatter acc -> LDS (C/D map: row = quad*4+r, col = n16)
  // token t = wave*64 + m*16 + quad*4 + r; addressing identical to R11/R12.
  #pragma unroll
  for (int m = 0; m < 4; ++m) {
    int g = wave * 2 + (m >> 1);
    int jt = (m & 1) * 4;
    int T0 = wave * 64 + m * 16 + quad * 4;
    unsigned q00 = cvt_pk_bf16(acc[m][0][0], acc[m][0][1]);
    unsigned q01 = cvt_pk_bf16(acc[m][0][2], acc[m][0][3]);
    unsigned q10 = cvt_pk_bf16(acc[m][1][0], acc[m][1][1]);
    unsigned q11 = cvt_pk_bf16(acc[m][1][2], acc[m][1][3]);
    unsigned k00 = cvt_pk_bf16(acc[m][2][0], acc[m][2][1]);
    unsigned k01 = cvt_pk_bf16(acc[m][2][2], acc[m][2][3]);
    unsigned k10 = cvt_pk_bf16(acc[m][3][0], acc[m][3][1]);
    unsigned k11 = cvt_pk_bf16(acc[m][3][2], acc[m][3][3]);
    sQ[(T0 + 0) * 40 + n16] = (bfu)q00;
    sQ[(T0 + 1) * 40 + n16] = (bfu)(q00 >> 16);
    sQ[(T0 + 2) * 40 + n16] = (bfu)q01;
    sQ[(T0 + 3) * 40 + n16] = (bfu)(q01 >> 16);
    sQ[(T0 + 0) * 40 + 16 + n16] = (bfu)q10;
    sQ[(T0 + 1) * 40 + 16 + n16] = (bfu)(q10 >> 16);
    sQ[(T0 + 2) * 40 + 16 + n16] = (bfu)q11;
    sQ[(T0 + 3) * 40 + 16 + n16] = (bfu)(q11 >> 16);
    sK[(T0 + 0) * 40 + n16] = (bfu)k00;
    sK[(T0 + 1) * 40 + n16] = (bfu)(k00 >> 16);
    sK[(T0 + 2) * 40 + n16] = (bfu)k01;
    sK[(T0 + 3) * 40 + n16] = (bfu)(k01 >> 16);
    sK[(T0 + 0) * 40 + 16 + n16] = (bfu)k10;
    sK[(T0 + 1) * 40 + 16 + n16] = (bfu)(k10 >> 16);
    sK[(T0 + 2) * 40 + 16 + n16] = (bfu)k11;
    sK[(T0 + 3) * 40 + 16 + n16] = (bfu)(k11 >> 16);
    unsigned v0 = cvt_pk_bf16(acc[m][4][0], acc[m][4][1]);
    unsigned v1 = cvt_pk_bf16(acc[m][4][2], acc[m][4][3]);
    unsigned v2 = cvt_pk_bf16(acc[m][5][0], acc[m][5][1]);
    unsigned v3 = cvt_pk_bf16(acc[m][5][2], acc[m][5][3]);
    int vbase = (g * 4 + quad) * 264 + jt;
    *(uint2*)&vperm[vbase + n16 * 8] = make_uint2(v0, v1);
    *(uint2*)&vperm[vbase + (16 + n16) * 8] = make_uint2(v2, v3);
  }
  __syncthreads();

  // ---- attention (R12-verified body) ----
  const f32x4 zero = {0.f, 0.f, 0.f, 0.f};
  const float scale = 0.17677669529663687f;  // 1/sqrt(32)
  for (int mi = 0; mi < 4; ++mi) {
    int mt = wave * 4 + mi;
    bf16x8 qf = *(const bf16x8*)&sQ[(mt * 16 + n16) * 40 + quad * 8];
    f32x4 st[16];
    #pragma unroll
    for (int T = 0; T < 16; ++T) {
      bf16x8 kf = *(const bf16x8*)&sK[(T * 16 + n16) * 40 + quad * 8];
      st[T] = __builtin_amdgcn_mfma_f32_16x16x32_bf16(kf, qf, zero, 0, 0, 0);
    }
    float m = st[0][0];
    #pragma unroll
    for (int T = 0; T < 16; ++T)
      #pragma unroll
      for (int r = 0; r < 4; ++r) m = fmaxf(m, st[T][r]);
    m = fmaxf(m, __shfl_xor(m, 16, 64));
    m = fmaxf(m, __shfl_xor(m, 32, 64));
    float l = 0.f;
    #pragma unroll
    for (int T = 0; T < 16; ++T)
      #pragma unroll
      for (int r = 0; r < 4; ++r) {
        float p = __expf((st[T][r] - m) * scale);
        st[T][r] = p;
        l += p;
      }
    l += __shfl_xor(l, 16, 64);
    l += __shfl_xor(l, 32, 64);
    float inv = 1.0f / l;
    f32x4 oa0 = zero, oa1 = zero;
    #pragma unroll
    for (int g = 0; g < 8; ++g) {
      uint4 pw = make_uint4(cvt_pk_bf16(st[2 * g][0], st[2 * g][1]),
                            cvt_pk_bf16(st[2 * g][2], st[2 * g][3]),
                            cvt_pk_bf16(st[2 * g + 1][0], st[2 * g + 1][1]),
                            cvt_pk_bf16(st[2 * g + 1][2], st[2 * g + 1][3]));
      bf16x8 pf = *(bf16x8*)&pw;
      bf16x8 va = *(const bf16x8*)&vperm[(g * 4 + quad) * 264 + n16 * 8];
      bf16x8 vb = *(const bf16x8*)&vperm[(g * 4 + quad) * 264 + (16 + n16) * 8];
      oa0 = __builtin_amdgcn_mfma_f32_16x16x32_bf16(va, pf, oa0, 0, 0, 0);
      oa1 = __builtin_amdgcn_mfma_f32_16x16x32_bf16(vb, pf, oa1, 0, 0, 0);
    }
    bfu* ob = o + ((size_t)reg * 256 + mt * 16 + n16) * 128 + h * 32 + quad * 4;
    unsigned o0 = cvt_pk_bf16(oa0[0] * inv, oa0[1] * inv);
    unsigned o1 = cvt_pk_bf16(oa0[2] * inv, oa0[3] * inv);
    unsigned o2 = cvt_pk_bf16(oa1[0] * inv, oa1[1] * inv);
    unsigned o3 = cvt_pk_bf16(oa1[2] * inv, oa1[3] * inv);
    *(uint2*)&ob[0] = make_uint2(o0, o1);
    *(uint2*)&ob[16] = make_uint2(o2, o3);
  }
}

// K4: tok[t][c] (bf16) += o @ w_out + b_out via MFMA, LDS-free.
__global__ __launch_bounds__(256) void k4_outproj(
    const bfu* __restrict__ o, const bfu* __restrict__ awout,
    const float* __restrict__ bout, bfu* __restrict__ tok) {
  int reg = blockIdx.x;
  int tt = blockIdx.y;
  int tid = threadIdx.x;
  int wave = tid >> 6, lane = tid & 63;
  int quad = lane >> 4, n16 = lane & 15;
  int t = tt * 64 + wave * 16 + n16;
  const bfu* ob = o + ((size_t)reg * 256 + t) * 128;
  f32x4 acc[8];
  #pragma unroll
  for (int mt = 0; mt < 8; ++mt) acc[mt] = (f32x4){0.f, 0.f, 0.f, 0.f};
  #pragma unroll
  for (int kt = 0; kt < 4; ++kt) {
    bf16x8 bfrag = *(const bf16x8*)&ob[kt * 32 + quad * 8];
    const bfu* arow = awout + ((size_t)(kt * 4 + quad) * 128 + n16) * 8;
    #pragma unroll
    for (int mt = 0; mt < 8; ++mt) {
      bf16x8 afrag = *(const bf16x8*)&arow[mt * 128];
      acc[mt] = __builtin_amdgcn_mfma_f32_16x16x32_bf16(afrag, bfrag, acc[mt], 0, 0, 0);
    }
  }
  bfu* tokr = tok + (size_t)reg * DIMC * TT + (size_t)t * DIMC;  // [t][c] row
  #pragma unroll
  for (int mt = 0; mt < 8; ++mt) {
    #pragma unroll
    for (int rp = 0; rp < 2; ++rp) {
      int c = mt * 16 + quad * 4 + rp * 2;
      unsigned old = *(const unsigned*)&tokr[c];
      float v0 = bf2f((bfu)old) + acc[mt][rp * 2] + bout[c];
      float v1 = bf2f((bfu)(old >> 16)) + acc[mt][rp * 2 + 1] + bout[c + 1];
      *(unsigned*)&tokr[c] = cvt_pk_bf16(v0, v1);
    }
  }
}

// K5: overlap merge (bf16 tok [reg][t][c]) -> xf fp32 + xln bf16 blocked.
__global__ __launch_bounds__(512) void k5_merge(
    const bfu* __restrict__ tok, const float* __restrict__ ln2g,
    const float* __restrict__ ln2b, float* __restrict__ xf,
    bfu* __restrict__ xln) {
  int hh = blockIdx.x, b = blockIdx.y;
  int tid = threadIdx.x;
  int w = tid & 127, q = tid >> 7;
  int ilo = (hh >= 2) ? (hh - 2) / 14 : 0;
  int ihi = hh / 14;
  if (ihi > 8) ihi = 8;
  int jlo = (w >= 2) ? (w - 2) / 14 : 0;
  int jhi = w / 14;
  if (jhi > 8) jhi = 8;
  float rcnt = 1.0f / (float)((ihi - ilo + 1) * (jhi - jlo + 1));
  size_t offs[4];
  int nij = 0;
  for (int i = ilo; i <= ihi; ++i)
    for (int j = jlo; j <= jhi; ++j) {
      int reg = b * NREGB + i * NR + j;
      int r = hh - i * STEP, s = w - j * STEP;
      offs[nij++] = (size_t)reg * DIMC * TT + (size_t)(r * 16 + s) * DIMC;
    }
  float* xp = xf + ((size_t)b * DIMC << 14) + hh * WW_ + w;
  float mm[32];
  float sum = 0.f, sq = 0.f;
  int c0 = q * 32;
  #pragma unroll
  for (int gl = 0; gl < 4; ++gl) {
    int cb = c0 + gl * 8;
    float v[8];
    #pragma unroll
    for (int jj = 0; jj < 8; ++jj) v[jj] = 0.f;
    for (int k = 0; k < nij; ++k) {
      uint4 u = *(const uint4*)&tok[offs[k] + cb];
      v[0] += bf2f((bfu)u.x);
      v[1] += bf2f((bfu)(u.x >> 16));
      v[2] += bf2f((bfu)u.y);
      v[3] += bf2f((bfu)(u.y >> 16));
      v[4] += bf2f((bfu)u.z);
      v[5] += bf2f((bfu)(u.z >> 16));
      v[6] += bf2f((bfu)u.w);
      v[7] += bf2f((bfu)(u.w >> 16));
    }
    #pragma unroll
    for (int jj = 0; jj < 8; ++jj) {
      float m = v[jj] * rcnt;
      xp[(size_t)(cb + jj) << 14] = m;
      mm[gl * 8 + jj] = m;
      sum += m;
      sq = fmaf(m, m, sq);
    }
  }
  __shared__ float rs[512];
  __shared__ float rq[512];
  __shared__ float muS[128];
  __shared__ float rsdS[128];
  rs[tid] = sum;
  rq[tid] = sq;
  __syncthreads();
  if (tid < 128) {
    float s4 = rs[tid] + rs[tid + 128] + rs[tid + 256] + rs[tid + 384];
    float q4 = rq[tid] + rq[tid + 128] + rq[tid + 256] + rq[tid + 384];
    float mu = s4 * (1.0f / DIMC);
    float var = q4 * (1.0f / DIMC) - mu * mu;
    muS[tid] = mu;
    rsdS[tid] = rsqrtf(var + 1e-5f);
  }
  __syncthreads();
  float mu = muS[w], rstd = rsdS[w];
  int p = hh * WW_ + w;
  #pragma unroll
  for (int gl = 0; gl < 4; ++gl) {
    int gidx = q * 4 + gl;
    float y[8];
    #pragma unroll
    for (int j = 0; j < 8; ++j) {
      int c = gidx * 8 + j;
      y[j] = (mm[gl * 8 + j] - mu) * rstd * ln2g[c] + ln2b[c];
    }
    uint4 pk = make_uint4(cvt_pk_bf16(y[0], y[1]), cvt_pk_bf16(y[2], y[3]),
                          cvt_pk_bf16(y[4], y[5]), cvt_pk_bf16(y[6], y[7]));
    *(uint4*)&xln[(((size_t)(b * 16 + gidx) << 14) + p) * 8] = pk;
  }
}

// K6: ym[b][f][p] = xln @ w_p0 + b_p0 via MFMA
__global__ __launch_bounds__(256) void k6_p0(
    const bfu* __restrict__ xln, const bfu* __restrict__ ap0,
    const float* __restrict__ bp0, bfu* __restrict__ ym) {
  int b = blockIdx.y;
  int ptile = blockIdx.x * 64;
  int tid = threadIdx.x;
  int wv = tid >> 6, lane = tid & 63;
  int quad = lane >> 4, n16 = lane & 15;
  int p = ptile + wv * 16 + n16;
  f32x4 acc[16];
  #pragma unroll
  for (int mt = 0; mt < 16; ++mt) acc[mt] = (f32x4){0.f, 0.f, 0.f, 0.f};
  #pragma unroll
  for (int ph = 0; ph < 4; ++ph) {
    int gg = ph * 4 + quad;
    bf16x8 bfrag = *(const bf16x8*)&xln[(((size_t)(b * 16 + gg) << 14) + p) * 8];
    const bfu* arow = ap0 + ((size_t)gg * 256 + n16) * 8;
    #pragma unroll
    for (int mt = 0; mt < 16; ++mt) {
      bf16x8 afrag = *(const bf16x8*)&arow[mt * 128];
      acc[mt] = __builtin_amdgcn_mfma_f32_16x16x32_bf16(afrag, bfrag, acc[mt], 0, 0, 0);
    }
  }
  #pragma unroll
  for (int mt = 0; mt < 16; ++mt) {
    #pragma unroll
    for (int rp = 0; rp < 2; ++rp) {
      int f = mt * 16 + quad * 4 + rp * 2;
      float v0 = acc[mt][rp * 2] + bp0[f];
      float v1 = acc[mt][rp * 2 + 1] + bp0[f + 1];
      unsigned pk = cvt_pk_bf16(v0, v1);
      ym[((size_t)(b * HID + f) << 14) + p] = (bfu)pk;
      ym[((size_t)(b * HID + f + 1) << 14) + p] = (bfu)(pk >> 16);
    }
  }
}

// K7: 5x5 depthwise conv, whole plane in LDS, fused BN partials
__global__ __launch_bounds__(256) void k7_conv(
    const bfu* __restrict__ ym, const float* __restrict__ dwk,
    bfu* __restrict__ ym2, float* __restrict__ bnacc) {
  int bf = blockIdx.x;
  int f = bf & (HID - 1);
  __shared__ bfu sp[128 * 134];
  const bfu* in = ym + ((size_t)bf << 14);
  int tid = threadIdx.x;
  for (int idx = tid; idx < 2048; idx += 256) {
    int r = idx >> 4, c8 = (idx & 15) << 3;
    ushort4 a = *(const ushort4*)&in[(r << 7) + c8];
    ushort4 b = *(const ushort4*)&in[(r << 7) + c8 + 4];
    bfu* d = &sp[r * 134 + c8];
    d[0] = a.x; d[1] = a.y; d[2] = a.z; d[3] = a.w;
    d[4] = b.x; d[5] = b.y; d[6] = b.z; d[7] = b.w;
  }
  float wk[25];
  #pragma unroll
  for (int i = 0; i < 25; ++i) wk[i] = dwk[f * 25 + i];
  __syncthreads();
  int row = tid >> 1, half = (tid & 1) << 6;
  float acc[64];
  #pragma unroll
  for (int i = 0; i < 64; ++i) acc[i] = 0.f;
  #pragma unroll
  for (int ky = 0; ky < 5; ++ky) {
    int y = row + ky - 2;
    if (y < 0 || y >= 128) continue;
    const bfu* rp = &sp[y * 134];
    float win[68];
    #pragma unroll
    for (int c = 0; c < 68; ++c) {
      int cc = half + c - 2;
      win[c] = (cc >= 0 && cc < 128) ? bf2f(rp[cc]) : 0.f;
    }
    #pragma unroll
    for (int kx = 0; kx < 5; ++kx) {
      float wv = wk[ky * 5 + kx];
      #pragma unroll
      for (int i = 0; i < 64; ++i) acc[i] = fmaf(win[i + kx], wv, acc[i]);
    }
  }
  float s = 0.f, sq = 0.f;
  #pragma unroll
  for (int i = 0; i < 64; ++i) {
    s += acc[i];
    sq = fmaf(acc[i], acc[i], sq);
  }
  bfu* op = ym2 + ((size_t)bf << 14) + (row << 7) + half;
  #pragma unroll
  for (int g8 = 0; g8 < 8; ++g8) {
    uint4 pk = make_uint4(cvt_pk_bf16(acc[g8 * 8 + 0], acc[g8 * 8 + 1]),
                          cvt_pk_bf16(acc[g8 * 8 + 2], acc[g8 * 8 + 3]),
                          cvt_pk_bf16(acc[g8 * 8 + 4], acc[g8 * 8 + 5]),
                          cvt_pk_bf16(acc[g8 * 8 + 6], acc[g8 * 8 + 7]));
    *(uint4*)&op[g8 * 8] = pk;
  }
  __syncthreads();
  float* red = (float*)sp;
  red[tid] = s;
  red[256 + tid] = sq;
  __syncthreads();
  for (int o = 128; o > 0; o >>= 1) {
    if (tid < o) {
      red[tid] += red[tid + o];
      red[256 + tid] += red[256 + tid + o];
    }
    __syncthreads();
  }
  if (tid == 0) {
    atomicAdd(&bnacc[f], red[0]);
    atomicAdd(&bnacc[HID + f], red[256]);
  }
}

// K10: out = gelu(gelu(bn(ym2))) @ w_p2 + b_p2 + xf via MFMA.
// BN finalize folded into a block prologue; gelu_fast (R17-verified).
__global__ __launch_bounds__(256) void k10_p2(
    const bfu* __restrict__ ym2, const float* __restrict__ bnacc,
    const float* __restrict__ bng, const float* __restrict__ bnb,
    const bfu* __restrict__ ap2, const float* __restrict__ bp2,
    const float* __restrict__ xf, float* __restrict__ outp) {
  int b = blockIdx.y;
  int ptile = blockIdx.x * 64;
  int tid = threadIdx.x;
  __shared__ float sA[HID];
  __shared__ float sB[HID];
  {
    float mu = bnacc[tid] * (1.0f / 65536.f);
    float var = bnacc[HID + tid] * (1.0f / 65536.f) - mu * mu;
    float sa = rsqrtf(var + 1e-5f) * bng[tid];
    sA[tid] = sa;
    sB[tid] = bnb[tid] - mu * sa;
  }
  __syncthreads();
  int wv = tid >> 6, lane = tid & 63;
  int quad = lane >> 4, n16 = lane & 15;
  int p = ptile + wv * 16 + n16;
  f32x4 acc[8];
  #pragma unroll
  for (int mt = 0; mt < 8; ++mt) acc[mt] = (f32x4){0.f, 0.f, 0.f, 0.f};
  #pragma unroll
  for (int ph = 0; ph < 8; ++ph) {
    int gg = ph * 4 + quad;
    const bfu* ymp = ym2 + (((size_t)(b * HID + gg * 8)) << 14) + p;
    float vals[8];
    #pragma unroll
    for (int j = 0; j < 8; ++j) vals[j] = bf2f(ymp[(size_t)j << 14]);
    float gv[8];
    #pragma unroll
    for (int j = 0; j < 8; ++j) {
      float v = fmaf(vals[j], sA[gg * 8 + j], sB[gg * 8 + j]);
      gv[j] = gelu_fast(gelu_fast(v));
    }
    uint4 pk = make_uint4(cvt_pk_bf16(gv[0], gv[1]), cvt_pk_bf16(gv[2], gv[3]),
                          cvt_pk_bf16(gv[4], gv[5]), cvt_pk_bf16(gv[6], gv[7]));
    bf16x8 bfrag = *(bf16x8*)&pk;
    const bfu* arow = ap2 + ((size_t)gg * 128 + n16) * 8;
    #pragma unroll
    for (int mt = 0; mt < 8; ++mt) {
      bf16x8 afrag = *(const bf16x8*)&arow[mt * 128];
      acc[mt] = __builtin_amdgcn_mfma_f32_16x16x32_bf16(afrag, bfrag, acc[mt], 0, 0, 0);
    }
  }
  #pragma unroll
  for (int mt = 0; mt < 8; ++mt) {
    #pragma unroll
    for (int r = 0; r < 4; ++r) {
      int c = mt * 16 + quad * 4 + r;
      size_t off = ((size_t)(b * DIMC + c) << 14) + p;
      outp[off] = acc[mt][r] + bp2[c] + xf[off];
    }
  }
}

extern "C" void kernel_launch(void* const* d_in, const int* in_sizes, int n_in,
                              void* d_out, int out_size, void* d_ws,
                              size_t ws_size, hipStream_t stream) {
  const float* x = (const float*)d_in[0];
  const float* ln1_g = (const float*)d_in[1];
  const float* ln1_b = (const float*)d_in[2];
  const float* w_qkv = (const float*)d_in[3];
  const float* w_out = (const float*)d_in[4];
  const float* b_out = (const float*)d_in[5];
  const float* ln2_g = (const float*)d_in[6];
  const float* ln2_b = (const float*)d_in[7];
  const float* w_p0 = (const float*)d_in[8];
  const float* b_p0 = (const float*)d_in[9];
  const float* dw_k = (const float*)d_in[10];
  const float* bn_g = (const float*)d_in[11];
  const float* bn_b = (const float*)d_in[12];
  const float* w_p2 = (const float*)d_in[13];
  const float* b_p2 = (const float*)d_in[14];
  float* outp = (float*)d_out;

  char* ws = (char*)d_ws;
  size_t off = 0;
  auto alloc = [&](size_t bytes) {
    void* p = ws + off;
    off += (bytes + 1023) & ~(size_t)1023;
    return p;
  };
  bfu* tok = (bfu*)alloc((size_t)NREG * DIMC * TT * 2);
  float* xf = (float*)alloc((size_t)BB * DIMC * HW * 4);
  bfu* xln = (bfu*)alloc((size_t)BB * DIMC * HW * 2);
  bfu* ym = (bfu*)alloc((size_t)BB * HID * HW * 2);
  bfu* ym2 = (bfu*)alloc((size_t)BB * HID * HW * 2);
  float* bnacc = (float*)alloc(2 * HID * 4);
  bfu* wqkvT = (bfu*)alloc(16 * 3072 * 2);
  bfu* ap0 = (bfu*)alloc(16 * 256 * 8 * 2);
  bfu* ap2 = (bfu*)alloc(32 * 128 * 8 * 2);
  bfu* awout = (bfu*)alloc(16 * 128 * 8 * 2);
  // overlays (lifetimes disjoint)
  bfu* o = ym;     // used k23->k4; ym written first in k6
  bfu* aln = ym2;  // used k1->k23; ym2 written first in k7

  // k1 grid: NREG gather blocks (512 thr) + 65 weight-prep blocks (tid<256)
  k1_gather<<<NREG + 65, 512, 0, stream>>>(x, ln1_g, ln1_b, tok, aln, w_qkv,
                                           w_p0, w_p2, w_out, wqkvT, ap0, ap2,
                                           awout, bnacc);
  k23_fused<<<dim3(NREG, NHEADS), 256, 0, stream>>>(aln, wqkvT, o);
  k4_outproj<<<dim3(NREG, 4), 256, 0, stream>>>(o, awout, b_out, tok);
  k5_merge<<<dim3(HH_, BB), 512, 0, stream>>>(tok, ln2_g, ln2_b, xf, xln);
  k6_p0<<<dim3(256, BB), 256, 0, stream>>>(xln, ap0, b_p0, ym);
  k7_conv<<<BB * HID, 256, 0, stream>>>(ym, dw_k, ym2, bnacc);
  k10_p2<<<dim3(256, BB), 256, 0, stream>>>(ym2, bnacc, bn_g, bn_b, ap2, b_p2,
                                            xf, outp);
}